// Round 3
// baseline (583.073 us; speedup 1.0000x reference)
//
#include <hip/hip_runtime.h>
#include <hip/hip_bf16.h>

typedef __bf16 bf16;
typedef __bf16 bf16x8 __attribute__((ext_vector_type(8)));
typedef float  f32x4  __attribute__((ext_vector_type(4)));

#define S_SP 3136              // 56*56
#define SCALE_V (1.0f/896.0f)  // (56*56*256)^-0.5, exact (896^2 = 802816)

__device__ __forceinline__ float bf2f(bf16 x) { return (float)x; }

// load 8 consecutive elements as bf16x8 (f32 source converts)
__device__ __forceinline__ bf16x8 load8(const float* p) {
    f32x4 a = *(const f32x4*)p;
    f32x4 b = *(const f32x4*)(p + 4);
    bf16x8 r;
    r[0] = (bf16)a[0]; r[1] = (bf16)a[1]; r[2] = (bf16)a[2]; r[3] = (bf16)a[3];
    r[4] = (bf16)b[0]; r[5] = (bf16)b[1]; r[6] = (bf16)b[2]; r[7] = (bf16)b[3];
    return r;
}
__device__ __forceinline__ bf16x8 load8(const bf16* p) { return *(const bf16x8*)p; }

// ---------------------------------------------------------------------------
// conv1x1 as GEMM: Y[b,o,s] = epilogue( sum_c W[o,c] * X[b,c,s] )
// block = 256 threads (4 waves); tile M = MT*64 (o) x N=64 (s); K-step 32.
// MT=4: one block computes ALL 256 outputs for its spatial tile -> X read once.
// Xt columns XOR-swizzled in 8-elem groups by row (8*36 dwords = 0 mod 32
// banks made staging writes 16-way conflicted; swizzle spreads rows).
// grid: (49, O/(MT*64), 16)
// ---------------------------------------------------------------------------
template<typename TX, typename TY, int CIN, int MT, bool LRELU, bool PAD_OUT>
__global__ __launch_bounds__(256)
void conv1x1_kernel(const TX* __restrict__ X, const float* __restrict__ W,
                    const float* __restrict__ bias, const float* __restrict__ bng,
                    const float* __restrict__ bnb, TY* __restrict__ Y, int O)
{
    __shared__ bf16 Xt[64][72];   // [s_local][c_local 0..31, group-swizzled]
    const int s0  = blockIdx.x * 64;
    const int o0  = blockIdx.y * (MT * 64);
    const int b   = blockIdx.z;
    const int tid = threadIdx.x;
    const int wv = tid >> 6, lane = tid & 63, li = lane & 15, quad = lane >> 4;

    const TX* Xb = X + (size_t)b * CIN * S_SP;

    f32x4 acc[MT][4];
    #pragma unroll
    for (int mt = 0; mt < MT; ++mt)
        #pragma unroll
        for (int nt = 0; nt < 4; ++nt) acc[mt][nt] = f32x4{0.f, 0.f, 0.f, 0.f};

    #pragma unroll
    for (int k0 = 0; k0 < CIN; k0 += 32) {
        if (k0) __syncthreads();
        {   // stage X[k0+cl][s0+sj..+8) -> Xt[sj..][swz(cl)]
            int cl  = tid >> 3;          // 0..31
            int sj  = (tid & 7) * 8;
            int g   = cl >> 3;           // column group 0..3
            int clo = cl & 7;
            bf16x8 v = load8(Xb + (size_t)(k0 + cl) * S_SP + s0 + sj);
            #pragma unroll
            for (int u = 0; u < 8; ++u) {
                int r  = sj + u;
                int gp = g ^ ((r >> 3) & 3);
                Xt[r][gp * 8 + clo] = v[u];
            }
        }
        __syncthreads();
        bf16x8 a[MT];
        #pragma unroll
        for (int mt = 0; mt < MT; ++mt)
            a[mt] = load8(W + (size_t)(o0 + mt * 64 + wv * 16 + li) * CIN + k0 + quad * 8);
        #pragma unroll
        for (int nt = 0; nt < 4; ++nt) {
            int row = nt * 16 + li;
            int gp  = quad ^ ((row >> 3) & 3);
            bf16x8 bb = *(const bf16x8*)&Xt[row][gp * 8];
            #pragma unroll
            for (int mt = 0; mt < MT; ++mt)
                acc[mt][nt] = __builtin_amdgcn_mfma_f32_16x16x32_bf16(a[mt], bb, acc[mt][nt], 0, 0, 0);
        }
    }

    const float rs = rsqrtf(1.0f + 1e-5f);
    #pragma unroll
    for (int mt = 0; mt < MT; ++mt) {
        #pragma unroll
        for (int r = 0; r < 4; ++r) {
            int o = o0 + mt * 64 + wv * 16 + quad * 4 + r;
            float bi = bias ? bias[o] : 0.f;
            float sc = bng ? bng[o] * rs : 1.f;
            float sh = bnb ? bnb[o] : 0.f;
            #pragma unroll
            for (int nt = 0; nt < 4; ++nt) {
                float v = acc[mt][nt][r] + bi;
                v = v * sc + sh;
                if (LRELU) v = (v >= 0.f) ? v : 0.2f * v;
                int s = s0 + nt * 16 + li;
                if (!PAD_OUT) {
                    Y[((size_t)b * O + o) * S_SP + s] = (TY)v;
                } else {
                    int rr = s / 56, cc = s % 56;
                    Y[(((size_t)b * O + o) * 58 + rr + 1) * 58 + cc + 1] = (TY)v;
                }
            }
        }
    }
}

// ---------------------------------------------------------------------------
// FUSED attention per (b,c):
//   phase 1 (local):  S = Q K^T (pad 56->64), row softmax, oacc = P V
//   phase 2 (global): P_g[h][k] = softmax_k(gs * GK[h][k]), oacc += P_g GV
// Vt columns XOR-swizzled in 8-elem groups by row (same aliasing fix as conv).
// grid 4096 x 256.
// ---------------------------------------------------------------------------
__global__ __launch_bounds__(256)
void attn_kernel(const bf16* __restrict__ Q, const bf16* __restrict__ K,
                 const bf16* __restrict__ V, const float* __restrict__ gq,
                 const bf16* __restrict__ GK, const bf16* __restrict__ GV,
                 bf16* __restrict__ F)
{
    __shared__ bf16 Qs[64][72], Ks[64][72], Vt[64][72], Ps[64][72];
    const int bc  = blockIdx.x;
    const int tid = threadIdx.x;
    const int wv = tid >> 6, lane = tid & 63, li = lane & 15, quad = lane >> 4;
    const int m0 = wv * 16;

    #pragma unroll
    for (int i = tid; i < 64 * 36; i += 256) {
        ((uint32_t*)Qs)[i] = 0; ((uint32_t*)Ks)[i] = 0;
        ((uint32_t*)Vt)[i] = 0; ((uint32_t*)Ps)[i] = 0;
    }
    __syncthreads();

    const bf16* Qp = Q + (size_t)bc * S_SP;
    const bf16* Kp = K + (size_t)bc * S_SP;
    const bf16* Vp = V + (size_t)bc * S_SP;
    for (int idx = tid; idx < 392; idx += 256) {   // 56 rows * 7 chunks of 8
        int r = idx / 7, cj = (idx % 7) * 8;
        *(bf16x8*)&Qs[r][cj] = *(const bf16x8*)(Qp + r * 56 + cj);
        *(bf16x8*)&Ks[r][cj] = *(const bf16x8*)(Kp + r * 56 + cj);
        bf16x8 vv = *(const bf16x8*)(Vp + r * 56 + cj);
        int q = r >> 3, rlo = r & 7;               // Vt[w=cj+u][swz(v=r)]
        #pragma unroll
        for (int u = 0; u < 8; ++u) {
            int row = cj + u;
            int gp  = q ^ ((row >> 3) & 3);
            Vt[row][gp * 8 + rlo] = vv[u];
        }
    }

    // ---- phase-2 prefetch: GV chunks (written to LDS after local PV) ----
    const float gs = gq[bc];
    const bf16* GVp = GV + (size_t)bc * S_SP;
    const bf16* GKp = GK + (size_t)bc * S_SP;
    const int ra  = tid / 7,            cja = (tid % 7) * 8;
    const bool hasb = tid < 136;        // idx = tid + 256 < 392
    const int rb  = (tid + 256) / 7,    cjb = ((tid + 256) % 7) * 8;
    bf16x8 gva = *(const bf16x8*)(GVp + ra * 56 + cja);
    bf16x8 gvb = hasb ? *(const bf16x8*)(GVp + rb * 56 + cjb) : bf16x8{};
    __syncthreads();

    // S = Q K^T : A[m=h][k=w]=Qs[h][w], B[k=w][n=v]=Ks[v][w]
    f32x4 sacc[4];
    #pragma unroll
    for (int nt = 0; nt < 4; ++nt) sacc[nt] = f32x4{0.f, 0.f, 0.f, 0.f};
    #pragma unroll
    for (int k0 = 0; k0 < 64; k0 += 32) {
        bf16x8 a = *(const bf16x8*)&Qs[m0 + li][k0 + quad * 8];
        #pragma unroll
        for (int nt = 0; nt < 4; ++nt) {
            bf16x8 bb = *(const bf16x8*)&Ks[nt * 16 + li][k0 + quad * 8];
            sacc[nt] = __builtin_amdgcn_mfma_f32_16x16x32_bf16(a, bb, sacc[nt], 0, 0, 0);
        }
    }

    // local row softmax: row = m0+quad*4+r, cols spread over (nt regs, li lanes)
    #pragma unroll
    for (int r = 0; r < 4; ++r) {
        float e[4]; float m = -3e38f;
        #pragma unroll
        for (int nt = 0; nt < 4; ++nt) {
            int v = nt * 16 + li;
            float x = (v < 56) ? sacc[nt][r] * SCALE_V : -3e38f;
            e[nt] = x; m = fmaxf(m, x);
        }
        m = fmaxf(m, __shfl_xor(m, 1)); m = fmaxf(m, __shfl_xor(m, 2));
        m = fmaxf(m, __shfl_xor(m, 4)); m = fmaxf(m, __shfl_xor(m, 8));
        float s = 0.f;
        #pragma unroll
        for (int nt = 0; nt < 4; ++nt) {
            float p = (nt * 16 + li < 56) ? __expf(e[nt] - m) : 0.f;
            e[nt] = p; s += p;
        }
        s += __shfl_xor(s, 1); s += __shfl_xor(s, 2);
        s += __shfl_xor(s, 4); s += __shfl_xor(s, 8);
        float inv = 1.f / s;
        int row = m0 + quad * 4 + r;
        #pragma unroll
        for (int nt = 0; nt < 4; ++nt) Ps[row][nt * 16 + li] = (bf16)(e[nt] * inv);
    }

    // ---- phase-2 prefetch: GK values for the global softmax (overlaps PV) ----
    float gkv[4][4];
    #pragma unroll
    for (int r = 0; r < 4; ++r) {
        int row = m0 + quad * 4 + r;
        int hrow = (row < 56) ? row : 0;            // rows >=56 discarded later
        #pragma unroll
        for (int nt = 0; nt < 4; ++nt) {
            int v = nt * 16 + li;
            gkv[r][nt] = (v < 56) ? bf2f(GKp[hrow * 56 + v]) : 0.f;
        }
    }
    __syncthreads();

    // oacc = P V : A[m=h][k=v]=Ps[h][v], B[k=v][n=w]=Vt[w][swz(v)]
    f32x4 oacc[4];
    #pragma unroll
    for (int nt = 0; nt < 4; ++nt) oacc[nt] = f32x4{0.f, 0.f, 0.f, 0.f};
    #pragma unroll
    for (int k0 = 0; k0 < 64; k0 += 32) {
        bf16x8 a = *(const bf16x8*)&Ps[m0 + li][k0 + quad * 8];
        int kq = (k0 >> 3) + quad;                  // k-group index (0..7)
        #pragma unroll
        for (int nt = 0; nt < 4; ++nt) {
            int row = nt * 16 + li;
            int gp  = kq ^ ((row >> 3) & 3);
            bf16x8 bb = *(const bf16x8*)&Vt[row][gp * 8];
            oacc[nt] = __builtin_amdgcn_mfma_f32_16x16x32_bf16(a, bb, oacc[nt], 0, 0, 0);
        }
    }

    // ---- phase 2: global attention, accumulate into oacc ----
    __syncthreads();   // local PV reads of Ps/Vt done; safe to overwrite

    // GV transpose into Vt (swizzled; pad region still zero from init)
    {
        int q = ra >> 3, rlo = ra & 7;
        #pragma unroll
        for (int u = 0; u < 8; ++u) {
            int row = cja + u;
            int gp  = q ^ ((row >> 3) & 3);
            Vt[row][gp * 8 + rlo] = gva[u];
        }
        if (hasb) {
            int qb = rb >> 3, rblo = rb & 7;
            #pragma unroll
            for (int u = 0; u < 8; ++u) {
                int row = cjb + u;
                int gp  = qb ^ ((row >> 3) & 3);
                Vt[row][gp * 8 + rblo] = gvb[u];
            }
        }
    }

    // global row softmax (wave-parallel, same layout as local)
    #pragma unroll
    for (int r = 0; r < 4; ++r) {
        float e[4]; float m = -3e38f;
        #pragma unroll
        for (int nt = 0; nt < 4; ++nt) {
            int v = nt * 16 + li;
            float x = (v < 56) ? gs * gkv[r][nt] : -3e38f;
            e[nt] = x; m = fmaxf(m, x);
        }
        m = fmaxf(m, __shfl_xor(m, 1)); m = fmaxf(m, __shfl_xor(m, 2));
        m = fmaxf(m, __shfl_xor(m, 4)); m = fmaxf(m, __shfl_xor(m, 8));
        float s = 0.f;
        #pragma unroll
        for (int nt = 0; nt < 4; ++nt) {
            float p = (nt * 16 + li < 56) ? __expf(e[nt] - m) : 0.f;
            e[nt] = p; s += p;
        }
        s += __shfl_xor(s, 1); s += __shfl_xor(s, 2);
        s += __shfl_xor(s, 4); s += __shfl_xor(s, 8);
        float inv = 1.f / s;
        int row = m0 + quad * 4 + r;
        #pragma unroll
        for (int nt = 0; nt < 4; ++nt) Ps[row][nt * 16 + li] = (bf16)(e[nt] * inv);
    }
    __syncthreads();

    // oacc += P_g GV
    #pragma unroll
    for (int k0 = 0; k0 < 64; k0 += 32) {
        bf16x8 a = *(const bf16x8*)&Ps[m0 + li][k0 + quad * 8];
        int kq = (k0 >> 3) + quad;
        #pragma unroll
        for (int nt = 0; nt < 4; ++nt) {
            int row = nt * 16 + li;
            int gp  = kq ^ ((row >> 3) & 3);
            bf16x8 bb = *(const bf16x8*)&Vt[row][gp * 8];
            oacc[nt] = __builtin_amdgcn_mfma_f32_16x16x32_bf16(a, bb, oacc[nt], 0, 0, 0);
        }
    }

    bf16* Fp = F + (size_t)bc * S_SP;
    #pragma unroll
    for (int r = 0; r < 4; ++r) {
        int h = m0 + quad * 4 + r;
        #pragma unroll
        for (int nt = 0; nt < 4; ++nt) {
            int w = nt * 16 + li;
            if (h < 56 && w < 56) Fp[h * 56 + w] = (bf16)oacc[nt][r];
        }
    }
}

// ---------------------------------------------------------------------------
__global__ __launch_bounds__(256)
void spatial_mean_kernel(const float* __restrict__ X, float* __restrict__ out)
{
    int bc = blockIdx.x, tid = threadIdx.x;
    const float* p = X + (size_t)bc * S_SP;
    float s = 0.f;
    for (int i = tid; i < S_SP; i += 256) s += p[i];
    for (int off = 32; off; off >>= 1) s += __shfl_down(s, off, 64);
    __shared__ float ws[4];
    if ((tid & 63) == 0) ws[tid >> 6] = s;
    __syncthreads();
    if (tid == 0) out[bc] = (ws[0] + ws[1] + ws[2] + ws[3]) * (1.0f / S_SP);
}

// Tiny global-branch MLP: grid 16 (per batch), 256 threads.
__global__ __launch_bounds__(256)
void gq_kernel(const float* __restrict__ pmean,
               const float* c11w, const float* c11b,
               const float* gaw1, const float* gab1, const float* gag1, const float* gabe1,
               const float* gaw2, const float* gab2, const float* gag2, const float* gabe2,
               float* __restrict__ gq)
{
    __shared__ float pm[256], p2[256], hh[64];
    int b = blockIdx.x, t = threadIdx.x;
    pm[t] = pmean[b * 256 + t];
    __syncthreads();
    float a = c11b[t];
    for (int c = 0; c < 256; ++c) a += c11w[t * 256 + c] * pm[c];
    p2[t] = a;
    __syncthreads();
    const float rs = rsqrtf(1.0f + 1e-5f);
    if (t < 64) {
        float h = gab1[t];
        for (int c = 0; c < 256; ++c) h += gaw1[t * 256 + c] * p2[c];
        h = h * (gag1[t] * rs) + gabe1[t];
        hh[t] = (h >= 0.f) ? h : 0.2f * h;
    }
    __syncthreads();
    float g = gab2[t];
    for (int i = 0; i < 64; ++i) g += gaw2[t * 64 + i] * hh[i];
    g = g * (gag2[t] * rs) + gabe2[t];
    gq[b * 256 + t] = g * SCALE_V;  // attention SCALE folded in
}

// Border-only fill: 228 border elems per 58x58 image (interior written by conv).
// grid = 16*256*228/256 = 3648 blocks exactly.
__global__ __launch_bounds__(256)
void fill_border_kernel(float* __restrict__ out, const float* __restrict__ c1b)
{
    int idx = blockIdx.x * 256 + threadIdx.x;
    int e  = idx % 228;
    int bo = idx / 228;
    if (bo >= 16 * 256) return;
    int o = bo & 255;
    int r, c;
    if (e < 58)       { r = 0;  c = e; }
    else if (e < 116) { r = 57; c = e - 58; }
    else { int t = e - 116; r = 1 + (t >> 1); c = (t & 1) * 57; }
    out[(size_t)bo * 3364 + r * 58 + c] = c1b[o];
}

// ---------------------------------------------------------------------------
extern "C" void kernel_launch(void* const* d_in, const int* in_sizes, int n_in,
                              void* d_out, int out_size, void* d_ws, size_t ws_size,
                              hipStream_t stream)
{
    (void)in_sizes; (void)n_in; (void)out_size; (void)ws_size;
    const float* x_s   = (const float*)d_in[0];
    const float* x_fq  = (const float*)d_in[1];
    const float* x_mt  = (const float*)d_in[2];
    const float* la_w1 = (const float*)d_in[3];
    const float* la_b1 = (const float*)d_in[4];
    const float* la_g1 = (const float*)d_in[5];
    const float* la_be1= (const float*)d_in[6];
    const float* la_w2 = (const float*)d_in[7];
    const float* la_b2 = (const float*)d_in[8];
    const float* la_g2 = (const float*)d_in[9];
    const float* la_be2= (const float*)d_in[10];
    const float* lk_w  = (const float*)d_in[11];
    const float* lk_b  = (const float*)d_in[12];
    const float* lv_w  = (const float*)d_in[13];
    const float* ga_w1 = (const float*)d_in[14];
    const float* ga_b1 = (const float*)d_in[15];
    const float* ga_g1 = (const float*)d_in[16];
    const float* ga_be1= (const float*)d_in[17];
    const float* ga_w2 = (const float*)d_in[18];
    const float* ga_b2 = (const float*)d_in[19];
    const float* ga_g2 = (const float*)d_in[20];
    const float* ga_be2= (const float*)d_in[21];
    const float* gk_w  = (const float*)d_in[22];
    const float* gk_b  = (const float*)d_in[23];
    const float* gv_w  = (const float*)d_in[24];
    const float* c11_w = (const float*)d_in[25];
    const float* c11_b = (const float*)d_in[26];
    const float* c1_w  = (const float*)d_in[27];
    const float* c1_b  = (const float*)d_in[28];
    float* out = (float*)d_out;

    char* ws = (char*)d_ws;
    const size_t SZ = (size_t)16 * 256 * S_SP * 2;       // 25,690,112 B (bf16)
    bf16* Q  = (bf16*)(ws);                              // aliased as F below
    bf16* K  = (bf16*)(ws + SZ);
    bf16* V  = (bf16*)(ws + 2 * SZ);
    bf16* GK = (bf16*)(ws + 3 * SZ);
    bf16* GV = (bf16*)(ws + 4 * SZ);
    bf16* Hd = (bf16*)(ws + 5 * SZ);                     // 16*64*3136 bf16
    float* pmean = (float*)(ws + 5 * SZ + (size_t)16 * 64 * S_SP * 2);
    float* gq    = pmean + 16 * 256;
    bf16* F  = Q;  // safe alias: each attn block reads only its own bc slice of Q
                   // (staged before any write) and writes only its own bc slice of F

    dim3 blk(256);
    // output border only (interior fully written by final conv)
    fill_border_kernel<<<dim3(3648), blk, 0, stream>>>(out, c1_b);

    // ---- local branch projections ----
    conv1x1_kernel<float, bf16, 256, 1, true,  false><<<dim3(49, 1, 16), blk, 0, stream>>>(
        x_s, la_w1, la_b1, la_g1, la_be1, Hd, 64);
    conv1x1_kernel<bf16, bf16, 64, 4,  false, false><<<dim3(49, 1, 16), blk, 0, stream>>>(
        Hd, la_w2, la_b2, la_g2, la_be2, Q, 256);
    conv1x1_kernel<float, bf16, 256, 4, false, false><<<dim3(49, 1, 16), blk, 0, stream>>>(
        x_s, lk_w, lk_b, nullptr, nullptr, K, 256);
    conv1x1_kernel<float, bf16, 256, 4, false, false><<<dim3(49, 1, 16), blk, 0, stream>>>(
        x_s, lv_w, nullptr, nullptr, nullptr, V, 256);

    // ---- global branch projections ----
    spatial_mean_kernel<<<dim3(4096), blk, 0, stream>>>(x_mt, pmean);
    gq_kernel<<<dim3(16), blk, 0, stream>>>(pmean, c11_w, c11_b,
        ga_w1, ga_b1, ga_g1, ga_be1, ga_w2, ga_b2, ga_g2, ga_be2, gq);
    conv1x1_kernel<float, bf16, 256, 4, false, false><<<dim3(49, 1, 16), blk, 0, stream>>>(
        x_fq, gk_w, gk_b, nullptr, nullptr, GK, 256);
    conv1x1_kernel<float, bf16, 256, 4, false, false><<<dim3(49, 1, 16), blk, 0, stream>>>(
        x_fq, gv_w, nullptr, nullptr, nullptr, GV, 256);

    // ---- fused local+global attention, writes F once ----
    attn_kernel<<<dim3(4096), blk, 0, stream>>>(Q, K, V, gq, GK, GV, F);

    // ---- output conv (writes interior of padded 58x58) ----
    conv1x1_kernel<bf16, float, 256, 4, false, true><<<dim3(49, 1, 16), blk, 0, stream>>>(
        F, c1_w, c1_b, nullptr, nullptr, out, 256);
}

// Round 4
// 508.367 us; speedup vs baseline: 1.1470x; 1.1470x over previous
//
#include <hip/hip_runtime.h>
#include <hip/hip_bf16.h>

typedef __bf16 bf16;
typedef __bf16 bf16x8 __attribute__((ext_vector_type(8)));
typedef float  f32x4  __attribute__((ext_vector_type(4)));

#define S_SP 3136              // 56*56
#define SCALE_V (1.0f/896.0f)  // (56*56*256)^-0.5, exact (896^2 = 802816)

__device__ __forceinline__ float bf2f(bf16 x) { return (float)x; }

// load 8 consecutive elements as bf16x8 (f32 source converts)
__device__ __forceinline__ bf16x8 load8(const float* p) {
    f32x4 a = *(const f32x4*)p;
    f32x4 b = *(const f32x4*)(p + 4);
    bf16x8 r;
    r[0] = (bf16)a[0]; r[1] = (bf16)a[1]; r[2] = (bf16)a[2]; r[3] = (bf16)a[3];
    r[4] = (bf16)b[0]; r[5] = (bf16)b[1]; r[6] = (bf16)b[2]; r[7] = (bf16)b[3];
    return r;
}
__device__ __forceinline__ bf16x8 load8(const bf16* p) { return *(const bf16x8*)p; }

// ---------------------------------------------------------------------------
// Multi-section conv1x1 over ONE f32 input (CIN=256): blockIdx.y picks the
// output section, so the grid (not per-block work) carries the output split:
//   sec 0..1 : Wa (+bias ba)            -> Ya, o0 = sec*128,   MT=2
//   sec 2..3 : Wb (no bias)             -> Yb, o0 = (sec-2)*128, MT=2
//   sec 4    : Wc (+ba/bn/LReLU), O=64  -> Yc, MT=1   (only if gridDim.y==5)
// All sections share the same staged X tile; L3 absorbs the cross-section
// re-reads (proven R1: 4 readers -> only 2x FETCH). 3920/3136 blocks restores
// occupancy that R3's MT=4 retile destroyed (65%->14.6%).
// Xt group-swizzle: 8*36 dwords = 0 mod 32 banks -> rows alias; XOR spreads.
// ---------------------------------------------------------------------------
__global__ __launch_bounds__(256)
void conv_multi_kernel(const float* __restrict__ X,
                       const float* __restrict__ Wa, const float* __restrict__ ba,
                       bf16* __restrict__ Ya,
                       const float* __restrict__ Wb, bf16* __restrict__ Yb,
                       const float* __restrict__ Wc, const float* __restrict__ bc,
                       const float* __restrict__ gc, const float* __restrict__ bec,
                       bf16* __restrict__ Yc)
{
    __shared__ bf16 Xt[64][72];
    const int s0  = blockIdx.x * 64;
    const int sec = blockIdx.y;
    const int b   = blockIdx.z;
    const int tid = threadIdx.x;
    const int wv = tid >> 6, lane = tid & 63, li = lane & 15, quad = lane >> 4;

    const float* Xb = X + (size_t)b * 256 * S_SP;

    // block-uniform section select
    const float* W; const float* bias = nullptr;
    const float* bng = nullptr; const float* bnb = nullptr;
    bf16* Y; int o0, O; bool two, lrelu = false;
    if (sec < 2)      { W = Wa; bias = ba; Y = Ya; o0 = sec * 128;       two = true;  O = 256; }
    else if (sec < 4) { W = Wb;            Y = Yb; o0 = (sec - 2) * 128; two = true;  O = 256; }
    else              { W = Wc; bias = bc; bng = gc; bnb = bec; Y = Yc;
                        o0 = 0; two = false; lrelu = true; O = 64; }

    f32x4 acc[2][4];
    #pragma unroll
    for (int mt = 0; mt < 2; ++mt)
        #pragma unroll
        for (int nt = 0; nt < 4; ++nt) acc[mt][nt] = f32x4{0.f, 0.f, 0.f, 0.f};

    #pragma unroll
    for (int k0 = 0; k0 < 256; k0 += 32) {
        if (k0) __syncthreads();
        {   // stage X[k0+cl][s0+sj..+8) -> Xt[sj..][swz(cl)]
            int cl  = tid >> 3;          // 0..31
            int sj  = (tid & 7) * 8;
            int g   = cl >> 3;           // column group 0..3
            int clo = cl & 7;
            bf16x8 v = load8(Xb + (size_t)(k0 + cl) * S_SP + s0 + sj);
            #pragma unroll
            for (int u = 0; u < 8; ++u) {
                int r  = sj + u;
                int gp = g ^ ((r >> 3) & 3);
                Xt[r][gp * 8 + clo] = v[u];
            }
        }
        __syncthreads();
        bf16x8 a0 = load8(W + (size_t)(o0 + wv * 16 + li) * 256 + k0 + quad * 8);
        bf16x8 a1;
        if (two) a1 = load8(W + (size_t)(o0 + 64 + wv * 16 + li) * 256 + k0 + quad * 8);
        #pragma unroll
        for (int nt = 0; nt < 4; ++nt) {
            int row = nt * 16 + li;
            int gp  = quad ^ ((row >> 3) & 3);
            bf16x8 bb = *(const bf16x8*)&Xt[row][gp * 8];
            acc[0][nt] = __builtin_amdgcn_mfma_f32_16x16x32_bf16(a0, bb, acc[0][nt], 0, 0, 0);
            if (two)
                acc[1][nt] = __builtin_amdgcn_mfma_f32_16x16x32_bf16(a1, bb, acc[1][nt], 0, 0, 0);
        }
    }

    const float rs = rsqrtf(1.0f + 1e-5f);
    const int nm = two ? 2 : 1;
    for (int mt = 0; mt < nm; ++mt) {
        #pragma unroll
        for (int r = 0; r < 4; ++r) {
            int o = o0 + mt * 64 + wv * 16 + quad * 4 + r;
            float bi = bias ? bias[o] : 0.f;
            float sc = bng ? bng[o] * rs : 1.f;
            float sh = bnb ? bnb[o] : 0.f;
            #pragma unroll
            for (int nt = 0; nt < 4; ++nt) {
                float v = acc[mt][nt][r] + bi;
                v = v * sc + sh;
                if (lrelu) v = (v >= 0.f) ? v : 0.2f * v;
                int s = s0 + nt * 16 + li;
                Y[((size_t)b * O + o) * S_SP + s] = (bf16)v;
            }
        }
    }
}

// ---------------------------------------------------------------------------
// Generic conv1x1 (kept for la_w2 and the final PAD conv), MT m-tiles/block.
// grid: (49, O/(MT*64), 16)
// ---------------------------------------------------------------------------
template<typename TX, typename TY, int CIN, int MT, bool LRELU, bool PAD_OUT>
__global__ __launch_bounds__(256)
void conv1x1_kernel(const TX* __restrict__ X, const float* __restrict__ W,
                    const float* __restrict__ bias, const float* __restrict__ bng,
                    const float* __restrict__ bnb, TY* __restrict__ Y, int O)
{
    __shared__ bf16 Xt[64][72];   // [s_local][c_local 0..31, group-swizzled]
    const int s0  = blockIdx.x * 64;
    const int o0  = blockIdx.y * (MT * 64);
    const int b   = blockIdx.z;
    const int tid = threadIdx.x;
    const int wv = tid >> 6, lane = tid & 63, li = lane & 15, quad = lane >> 4;

    const TX* Xb = X + (size_t)b * CIN * S_SP;

    f32x4 acc[MT][4];
    #pragma unroll
    for (int mt = 0; mt < MT; ++mt)
        #pragma unroll
        for (int nt = 0; nt < 4; ++nt) acc[mt][nt] = f32x4{0.f, 0.f, 0.f, 0.f};

    #pragma unroll
    for (int k0 = 0; k0 < CIN; k0 += 32) {
        if (k0) __syncthreads();
        {   // stage X[k0+cl][s0+sj..+8) -> Xt[sj..][swz(cl)]
            int cl  = tid >> 3;          // 0..31
            int sj  = (tid & 7) * 8;
            int g   = cl >> 3;           // column group 0..3
            int clo = cl & 7;
            bf16x8 v = load8(Xb + (size_t)(k0 + cl) * S_SP + s0 + sj);
            #pragma unroll
            for (int u = 0; u < 8; ++u) {
                int r  = sj + u;
                int gp = g ^ ((r >> 3) & 3);
                Xt[r][gp * 8 + clo] = v[u];
            }
        }
        __syncthreads();
        bf16x8 a[MT];
        #pragma unroll
        for (int mt = 0; mt < MT; ++mt)
            a[mt] = load8(W + (size_t)(o0 + mt * 64 + wv * 16 + li) * CIN + k0 + quad * 8);
        #pragma unroll
        for (int nt = 0; nt < 4; ++nt) {
            int row = nt * 16 + li;
            int gp  = quad ^ ((row >> 3) & 3);
            bf16x8 bb = *(const bf16x8*)&Xt[row][gp * 8];
            #pragma unroll
            for (int mt = 0; mt < MT; ++mt)
                acc[mt][nt] = __builtin_amdgcn_mfma_f32_16x16x32_bf16(a[mt], bb, acc[mt][nt], 0, 0, 0);
        }
    }

    const float rs = rsqrtf(1.0f + 1e-5f);
    #pragma unroll
    for (int mt = 0; mt < MT; ++mt) {
        #pragma unroll
        for (int r = 0; r < 4; ++r) {
            int o = o0 + mt * 64 + wv * 16 + quad * 4 + r;
            float bi = bias ? bias[o] : 0.f;
            float sc = bng ? bng[o] * rs : 1.f;
            float sh = bnb ? bnb[o] : 0.f;
            #pragma unroll
            for (int nt = 0; nt < 4; ++nt) {
                float v = acc[mt][nt][r] + bi;
                v = v * sc + sh;
                if (LRELU) v = (v >= 0.f) ? v : 0.2f * v;
                int s = s0 + nt * 16 + li;
                if (!PAD_OUT) {
                    Y[((size_t)b * O + o) * S_SP + s] = (TY)v;
                } else {
                    int rr = s / 56, cc = s % 56;
                    Y[(((size_t)b * O + o) * 58 + rr + 1) * 58 + cc + 1] = (TY)v;
                }
            }
        }
    }
}

// ---------------------------------------------------------------------------
// FUSED attention per (b,c):
//   phase 1 (local):  S = Q K^T (pad 56->64), row softmax, oacc = P V
//   phase 2 (global): P_g[h][k] = softmax_k(gs * GK[h][k]), oacc += P_g GV
// Vt columns XOR-swizzled in 8-elem groups by row (same aliasing fix as conv).
// grid 4096 x 256.
// ---------------------------------------------------------------------------
__global__ __launch_bounds__(256)
void attn_kernel(const bf16* __restrict__ Q, const bf16* __restrict__ K,
                 const bf16* __restrict__ V, const float* __restrict__ gq,
                 const bf16* __restrict__ GK, const bf16* __restrict__ GV,
                 bf16* __restrict__ F)
{
    __shared__ bf16 Qs[64][72], Ks[64][72], Vt[64][72], Ps[64][72];
    const int bc  = blockIdx.x;
    const int tid = threadIdx.x;
    const int wv = tid >> 6, lane = tid & 63, li = lane & 15, quad = lane >> 4;
    const int m0 = wv * 16;

    #pragma unroll
    for (int i = tid; i < 64 * 36; i += 256) {
        ((uint32_t*)Qs)[i] = 0; ((uint32_t*)Ks)[i] = 0;
        ((uint32_t*)Vt)[i] = 0; ((uint32_t*)Ps)[i] = 0;
    }
    __syncthreads();

    const bf16* Qp = Q + (size_t)bc * S_SP;
    const bf16* Kp = K + (size_t)bc * S_SP;
    const bf16* Vp = V + (size_t)bc * S_SP;
    for (int idx = tid; idx < 392; idx += 256) {   // 56 rows * 7 chunks of 8
        int r = idx / 7, cj = (idx % 7) * 8;
        *(bf16x8*)&Qs[r][cj] = *(const bf16x8*)(Qp + r * 56 + cj);
        *(bf16x8*)&Ks[r][cj] = *(const bf16x8*)(Kp + r * 56 + cj);
        bf16x8 vv = *(const bf16x8*)(Vp + r * 56 + cj);
        int q = r >> 3, rlo = r & 7;               // Vt[w=cj+u][swz(v=r)]
        #pragma unroll
        for (int u = 0; u < 8; ++u) {
            int row = cj + u;
            int gp  = q ^ ((row >> 3) & 3);
            Vt[row][gp * 8 + rlo] = vv[u];
        }
    }

    // ---- phase-2 prefetch: GV chunks (written to LDS after local PV) ----
    const float gs = gq[bc];
    const bf16* GVp = GV + (size_t)bc * S_SP;
    const bf16* GKp = GK + (size_t)bc * S_SP;
    const int ra  = tid / 7,            cja = (tid % 7) * 8;
    const bool hasb = tid < 136;        // idx = tid + 256 < 392
    const int rb  = (tid + 256) / 7,    cjb = ((tid + 256) % 7) * 8;
    bf16x8 gva = *(const bf16x8*)(GVp + ra * 56 + cja);
    bf16x8 gvb = hasb ? *(const bf16x8*)(GVp + rb * 56 + cjb) : bf16x8{};
    __syncthreads();

    // S = Q K^T : A[m=h][k=w]=Qs[h][w], B[k=w][n=v]=Ks[v][w]
    f32x4 sacc[4];
    #pragma unroll
    for (int nt = 0; nt < 4; ++nt) sacc[nt] = f32x4{0.f, 0.f, 0.f, 0.f};
    #pragma unroll
    for (int k0 = 0; k0 < 64; k0 += 32) {
        bf16x8 a = *(const bf16x8*)&Qs[m0 + li][k0 + quad * 8];
        #pragma unroll
        for (int nt = 0; nt < 4; ++nt) {
            bf16x8 bb = *(const bf16x8*)&Ks[nt * 16 + li][k0 + quad * 8];
            sacc[nt] = __builtin_amdgcn_mfma_f32_16x16x32_bf16(a, bb, sacc[nt], 0, 0, 0);
        }
    }

    // local row softmax: row = m0+quad*4+r, cols spread over (nt regs, li lanes)
    #pragma unroll
    for (int r = 0; r < 4; ++r) {
        float e[4]; float m = -3e38f;
        #pragma unroll
        for (int nt = 0; nt < 4; ++nt) {
            int v = nt * 16 + li;
            float x = (v < 56) ? sacc[nt][r] * SCALE_V : -3e38f;
            e[nt] = x; m = fmaxf(m, x);
        }
        m = fmaxf(m, __shfl_xor(m, 1)); m = fmaxf(m, __shfl_xor(m, 2));
        m = fmaxf(m, __shfl_xor(m, 4)); m = fmaxf(m, __shfl_xor(m, 8));
        float s = 0.f;
        #pragma unroll
        for (int nt = 0; nt < 4; ++nt) {
            float p = (nt * 16 + li < 56) ? __expf(e[nt] - m) : 0.f;
            e[nt] = p; s += p;
        }
        s += __shfl_xor(s, 1); s += __shfl_xor(s, 2);
        s += __shfl_xor(s, 4); s += __shfl_xor(s, 8);
        float inv = 1.f / s;
        int row = m0 + quad * 4 + r;
        #pragma unroll
        for (int nt = 0; nt < 4; ++nt) Ps[row][nt * 16 + li] = (bf16)(e[nt] * inv);
    }

    // ---- phase-2 prefetch: GK values for the global softmax (overlaps PV) ----
    float gkv[4][4];
    #pragma unroll
    for (int r = 0; r < 4; ++r) {
        int row = m0 + quad * 4 + r;
        int hrow = (row < 56) ? row : 0;            // rows >=56 discarded later
        #pragma unroll
        for (int nt = 0; nt < 4; ++nt) {
            int v = nt * 16 + li;
            gkv[r][nt] = (v < 56) ? bf2f(GKp[hrow * 56 + v]) : 0.f;
        }
    }
    __syncthreads();

    // oacc = P V : A[m=h][k=v]=Ps[h][v], B[k=v][n=w]=Vt[w][swz(v)]
    f32x4 oacc[4];
    #pragma unroll
    for (int nt = 0; nt < 4; ++nt) oacc[nt] = f32x4{0.f, 0.f, 0.f, 0.f};
    #pragma unroll
    for (int k0 = 0; k0 < 64; k0 += 32) {
        bf16x8 a = *(const bf16x8*)&Ps[m0 + li][k0 + quad * 8];
        int kq = (k0 >> 3) + quad;                  // k-group index (0..7)
        #pragma unroll
        for (int nt = 0; nt < 4; ++nt) {
            int row = nt * 16 + li;
            int gp  = kq ^ ((row >> 3) & 3);
            bf16x8 bb = *(const bf16x8*)&Vt[row][gp * 8];
            oacc[nt] = __builtin_amdgcn_mfma_f32_16x16x32_bf16(a, bb, oacc[nt], 0, 0, 0);
        }
    }

    // ---- phase 2: global attention, accumulate into oacc ----
    __syncthreads();   // local PV reads of Ps/Vt done; safe to overwrite

    // GV transpose into Vt (swizzled; pad region still zero from init)
    {
        int q = ra >> 3, rlo = ra & 7;
        #pragma unroll
        for (int u = 0; u < 8; ++u) {
            int row = cja + u;
            int gp  = q ^ ((row >> 3) & 3);
            Vt[row][gp * 8 + rlo] = gva[u];
        }
        if (hasb) {
            int qb = rb >> 3, rblo = rb & 7;
            #pragma unroll
            for (int u = 0; u < 8; ++u) {
                int row = cjb + u;
                int gp  = qb ^ ((row >> 3) & 3);
                Vt[row][gp * 8 + rblo] = gvb[u];
            }
        }
    }

    // global row softmax (wave-parallel, same layout as local)
    #pragma unroll
    for (int r = 0; r < 4; ++r) {
        float e[4]; float m = -3e38f;
        #pragma unroll
        for (int nt = 0; nt < 4; ++nt) {
            int v = nt * 16 + li;
            float x = (v < 56) ? gs * gkv[r][nt] : -3e38f;
            e[nt] = x; m = fmaxf(m, x);
        }
        m = fmaxf(m, __shfl_xor(m, 1)); m = fmaxf(m, __shfl_xor(m, 2));
        m = fmaxf(m, __shfl_xor(m, 4)); m = fmaxf(m, __shfl_xor(m, 8));
        float s = 0.f;
        #pragma unroll
        for (int nt = 0; nt < 4; ++nt) {
            float p = (nt * 16 + li < 56) ? __expf(e[nt] - m) : 0.f;
            e[nt] = p; s += p;
        }
        s += __shfl_xor(s, 1); s += __shfl_xor(s, 2);
        s += __shfl_xor(s, 4); s += __shfl_xor(s, 8);
        float inv = 1.f / s;
        int row = m0 + quad * 4 + r;
        #pragma unroll
        for (int nt = 0; nt < 4; ++nt) Ps[row][nt * 16 + li] = (bf16)(e[nt] * inv);
    }
    __syncthreads();

    // oacc += P_g GV
    #pragma unroll
    for (int k0 = 0; k0 < 64; k0 += 32) {
        bf16x8 a = *(const bf16x8*)&Ps[m0 + li][k0 + quad * 8];
        int kq = (k0 >> 3) + quad;
        #pragma unroll
        for (int nt = 0; nt < 4; ++nt) {
            int row = nt * 16 + li;
            int gp  = kq ^ ((row >> 3) & 3);
            bf16x8 bb = *(const bf16x8*)&Vt[row][gp * 8];
            oacc[nt] = __builtin_amdgcn_mfma_f32_16x16x32_bf16(a, bb, oacc[nt], 0, 0, 0);
        }
    }

    bf16* Fp = F + (size_t)bc * S_SP;
    #pragma unroll
    for (int r = 0; r < 4; ++r) {
        int h = m0 + quad * 4 + r;
        #pragma unroll
        for (int nt = 0; nt < 4; ++nt) {
            int w = nt * 16 + li;
            if (h < 56 && w < 56) Fp[h * 56 + w] = (bf16)oacc[nt][r];
        }
    }
}

// ---------------------------------------------------------------------------
__global__ __launch_bounds__(256)
void spatial_mean_kernel(const float* __restrict__ X, float* __restrict__ out)
{
    int bc = blockIdx.x, tid = threadIdx.x;
    const float* p = X + (size_t)bc * S_SP;
    float s = 0.f;
    for (int i = tid; i < S_SP; i += 256) s += p[i];
    for (int off = 32; off; off >>= 1) s += __shfl_down(s, off, 64);
    __shared__ float ws[4];
    if ((tid & 63) == 0) ws[tid >> 6] = s;
    __syncthreads();
    if (tid == 0) out[bc] = (ws[0] + ws[1] + ws[2] + ws[3]) * (1.0f / S_SP);
}

// Tiny global-branch MLP: grid 16 (per batch), 256 threads.
__global__ __launch_bounds__(256)
void gq_kernel(const float* __restrict__ pmean,
               const float* c11w, const float* c11b,
               const float* gaw1, const float* gab1, const float* gag1, const float* gabe1,
               const float* gaw2, const float* gab2, const float* gag2, const float* gabe2,
               float* __restrict__ gq)
{
    __shared__ float pm[256], p2[256], hh[64];
    int b = blockIdx.x, t = threadIdx.x;
    pm[t] = pmean[b * 256 + t];
    __syncthreads();
    float a = c11b[t];
    for (int c = 0; c < 256; ++c) a += c11w[t * 256 + c] * pm[c];
    p2[t] = a;
    __syncthreads();
    const float rs = rsqrtf(1.0f + 1e-5f);
    if (t < 64) {
        float h = gab1[t];
        for (int c = 0; c < 256; ++c) h += gaw1[t * 256 + c] * p2[c];
        h = h * (gag1[t] * rs) + gabe1[t];
        hh[t] = (h >= 0.f) ? h : 0.2f * h;
    }
    __syncthreads();
    float g = gab2[t];
    for (int i = 0; i < 64; ++i) g += gaw2[t * 64 + i] * hh[i];
    g = g * (gag2[t] * rs) + gabe2[t];
    gq[b * 256 + t] = g * SCALE_V;  // attention SCALE folded in
}

// Border-only fill: 228 border elems per 58x58 image (interior written by conv).
// grid = 16*256*228/256 = 3648 blocks exactly.
__global__ __launch_bounds__(256)
void fill_border_kernel(float* __restrict__ out, const float* __restrict__ c1b)
{
    int idx = blockIdx.x * 256 + threadIdx.x;
    int e  = idx % 228;
    int bo = idx / 228;
    if (bo >= 16 * 256) return;
    int o = bo & 255;
    int r, c;
    if (e < 58)       { r = 0;  c = e; }
    else if (e < 116) { r = 57; c = e - 58; }
    else { int t = e - 116; r = 1 + (t >> 1); c = (t & 1) * 57; }
    out[(size_t)bo * 3364 + r * 58 + c] = c1b[o];
}

// ---------------------------------------------------------------------------
extern "C" void kernel_launch(void* const* d_in, const int* in_sizes, int n_in,
                              void* d_out, int out_size, void* d_ws, size_t ws_size,
                              hipStream_t stream)
{
    (void)in_sizes; (void)n_in; (void)out_size; (void)ws_size;
    const float* x_s   = (const float*)d_in[0];
    const float* x_fq  = (const float*)d_in[1];
    const float* x_mt  = (const float*)d_in[2];
    const float* la_w1 = (const float*)d_in[3];
    const float* la_b1 = (const float*)d_in[4];
    const float* la_g1 = (const float*)d_in[5];
    const float* la_be1= (const float*)d_in[6];
    const float* la_w2 = (const float*)d_in[7];
    const float* la_b2 = (const float*)d_in[8];
    const float* la_g2 = (const float*)d_in[9];
    const float* la_be2= (const float*)d_in[10];
    const float* lk_w  = (const float*)d_in[11];
    const float* lk_b  = (const float*)d_in[12];
    const float* lv_w  = (const float*)d_in[13];
    const float* ga_w1 = (const float*)d_in[14];
    const float* ga_b1 = (const float*)d_in[15];
    const float* ga_g1 = (const float*)d_in[16];
    const float* ga_be1= (const float*)d_in[17];
    const float* ga_w2 = (const float*)d_in[18];
    const float* ga_b2 = (const float*)d_in[19];
    const float* ga_g2 = (const float*)d_in[20];
    const float* ga_be2= (const float*)d_in[21];
    const float* gk_w  = (const float*)d_in[22];
    const float* gk_b  = (const float*)d_in[23];
    const float* gv_w  = (const float*)d_in[24];
    const float* c11_w = (const float*)d_in[25];
    const float* c11_b = (const float*)d_in[26];
    const float* c1_w  = (const float*)d_in[27];
    const float* c1_b  = (const float*)d_in[28];
    float* out = (float*)d_out;

    char* ws = (char*)d_ws;
    const size_t SZ = (size_t)16 * 256 * S_SP * 2;       // 25,690,112 B (bf16)
    bf16* Q  = (bf16*)(ws);                              // aliased as F below
    bf16* K  = (bf16*)(ws + SZ);
    bf16* V  = (bf16*)(ws + 2 * SZ);
    bf16* GK = (bf16*)(ws + 3 * SZ);
    bf16* GV = (bf16*)(ws + 4 * SZ);
    bf16* Hd = (bf16*)(ws + 5 * SZ);                     // 16*64*3136 bf16
    float* pmean = (float*)(ws + 5 * SZ + (size_t)16 * 64 * S_SP * 2);
    float* gq    = pmean + 16 * 256;
    bf16* F  = Q;  // safe alias: each attn block reads only its own bc slice of Q
                   // (staged before any write) and writes only its own bc slice of F

    dim3 blk(256);
    // output border only (interior fully written by final conv)
    fill_border_kernel<<<dim3(3648), blk, 0, stream>>>(out, c1_b);

    // ---- local branch projections: lk, lv, la_w1 fused over x_s ----
    conv_multi_kernel<<<dim3(49, 5, 16), blk, 0, stream>>>(
        x_s, lk_w, lk_b, K, lv_w, V,
        la_w1, la_b1, la_g1, la_be1, Hd);
    conv1x1_kernel<bf16, bf16, 64, 2, false, false><<<dim3(49, 2, 16), blk, 0, stream>>>(
        Hd, la_w2, la_b2, la_g2, la_be2, Q, 256);

    // ---- global branch projections: gk, gv fused over x_fq ----
    spatial_mean_kernel<<<dim3(4096), blk, 0, stream>>>(x_mt, pmean);
    gq_kernel<<<dim3(16), blk, 0, stream>>>(pmean, c11_w, c11_b,
        ga_w1, ga_b1, ga_g1, ga_be1, ga_w2, ga_b2, ga_g2, ga_be2, gq);
    conv_multi_kernel<<<dim3(49, 4, 16), blk, 0, stream>>>(
        x_fq, gk_w, gk_b, GK, gv_w, GV,
        nullptr, nullptr, nullptr, nullptr, nullptr);

    // ---- fused local+global attention, writes F once ----
    attn_kernel<<<dim3(4096), blk, 0, stream>>>(Q, K, V, gq, GK, GV, F);

    // ---- output conv (writes interior of padded 58x58) ----
    conv1x1_kernel<bf16, float, 256, 2, false, true><<<dim3(49, 2, 16), blk, 0, stream>>>(
        F, c1_w, c1_b, nullptr, nullptr, out, 256);
}

// Round 5
// 497.041 us; speedup vs baseline: 1.1731x; 1.0228x over previous
//
#include <hip/hip_runtime.h>
#include <hip/hip_bf16.h>

typedef __bf16 bf16;
typedef __bf16 bf16x8 __attribute__((ext_vector_type(8)));
typedef float  f32x4  __attribute__((ext_vector_type(4)));

#define S_SP 3136              // 56*56
#define SCALE_V (1.0f/896.0f)  // (56*56*256)^-0.5, exact (896^2 = 802816)

__device__ __forceinline__ float bf2f(bf16 x) { return (float)x; }

__device__ __forceinline__ bf16x8 load8(const float* p) {
    f32x4 a = *(const f32x4*)p;
    f32x4 b = *(const f32x4*)(p + 4);
    bf16x8 r;
    r[0] = (bf16)a[0]; r[1] = (bf16)a[1]; r[2] = (bf16)a[2]; r[3] = (bf16)a[3];
    r[4] = (bf16)b[0]; r[5] = (bf16)b[1]; r[6] = (bf16)b[2]; r[7] = (bf16)b[3];
    return r;
}
__device__ __forceinline__ bf16x8 load8(const bf16* p) { return *(const bf16x8*)p; }

// raw (unconverted) 8-element prefetch vector, converted at LDS-write time
template<typename T> struct raw8;
template<> struct raw8<float> { f32x4 a, b; };
template<> struct raw8<bf16>  { bf16x8 v; };
__device__ __forceinline__ raw8<float> loadraw(const float* p) {
    return { *(const f32x4*)p, *(const f32x4*)(p + 4) };
}
__device__ __forceinline__ raw8<bf16> loadraw(const bf16* p) {
    return { *(const bf16x8*)p };
}
__device__ __forceinline__ bf16 elem8(const raw8<float>& r, int u) {
    return (bf16)(u < 4 ? r.a[u] : r.b[u - 4]);
}
__device__ __forceinline__ bf16 elem8(const raw8<bf16>& r, int u) { return r.v[u]; }

// ---------------------------------------------------------------------------
// Multi-section conv1x1 over ONE f32 input (CIN=256), XCD-chunked + pipelined.
// 1D grid 8*98*NSEC. Decode: xcd=wg&7, idx=wg>>3, sec=idx%NSEC, tile=xcd*98+idx/NSEC
//  -> the NSEC readers of one X tile differ by a multiple of 8 in block id =
//     SAME XCD = shared L2 (R4 showed 49-apart readers on different XCDs
//     refetched 2.5x from HBM).
// K-loop: LDS double-buffer + register prefetch, ONE barrier per K-step;
// next slab's global load is in flight across this step's barrier+MFMA.
// Sections: 0..1 Wa(+ba)->Ya o0=sec*128 | 2..3 Wb->Yb | 4 Wc(+bn,LReLU,O=64)->Yc
// ---------------------------------------------------------------------------
template<int NSEC>
__global__ __launch_bounds__(256)
void conv_multi_kernel(const float* __restrict__ X,
                       const float* __restrict__ Wa, const float* __restrict__ ba,
                       bf16* __restrict__ Ya,
                       const float* __restrict__ Wb, bf16* __restrict__ Yb,
                       const float* __restrict__ Wc, const float* __restrict__ bc,
                       const float* __restrict__ gc, const float* __restrict__ bec,
                       bf16* __restrict__ Yc)
{
    __shared__ bf16 Xt[2][64][72];
    const int wg  = blockIdx.x;
    const int xcd = wg & 7;
    const int idx = wg >> 3;
    const int sec = idx % NSEC;
    const int t   = idx / NSEC;
    const int tile = xcd * 98 + t;          // 0..783
    const int s0  = (tile % 49) * 64;
    const int b   = tile / 49;
    const int tid = threadIdx.x;
    const int wv = tid >> 6, lane = tid & 63, li = lane & 15, quad = lane >> 4;

    const float* Xb = X + (size_t)b * 256 * S_SP;

    // block-uniform section select
    const float* W; const float* bias = nullptr;
    const float* bng = nullptr; const float* bnb = nullptr;
    bf16* Y; int o0, O; bool two, lrelu = false;
    if (sec < 2)      { W = Wa; bias = ba; Y = Ya; o0 = sec * 128;       two = true;  O = 256; }
    else if (sec < 4) { W = Wb;            Y = Yb; o0 = (sec - 2) * 128; two = true;  O = 256; }
    else              { W = Wc; bias = bc; bng = gc; bnb = bec; Y = Yc;
                        o0 = 0; two = false; lrelu = true; O = 64; }

    f32x4 acc[2][4];
    #pragma unroll
    for (int mt = 0; mt < 2; ++mt)
        #pragma unroll
        for (int nt = 0; nt < 4; ++nt) acc[mt][nt] = f32x4{0.f, 0.f, 0.f, 0.f};

    const int cl  = tid >> 3;            // 0..31
    const int sj  = (tid & 7) * 8;
    const int g   = cl >> 3;             // column group 0..3
    const int clo = cl & 7;
    const float* xp = Xb + (size_t)cl * S_SP + s0 + sj;

    raw8<float> v = loadraw(xp);
    int p = 0;
    #pragma unroll
    for (int k0 = 0; k0 < 256; k0 += 32) {
        // write current slab regs -> Xt[p] (group-swizzled)
        #pragma unroll
        for (int u = 0; u < 8; ++u) {
            int r  = sj + u;
            int gp = g ^ ((r >> 3) & 3);
            Xt[p][r][gp * 8 + clo] = elem8(v, u);
        }
        raw8<float> vn = v;
        if (k0 + 32 < 256) vn = loadraw(xp + (size_t)(k0 + 32) * S_SP);
        __syncthreads();
        bf16x8 a0 = load8(W + (size_t)(o0 + wv * 16 + li) * 256 + k0 + quad * 8);
        bf16x8 a1;
        if (two) a1 = load8(W + (size_t)(o0 + 64 + wv * 16 + li) * 256 + k0 + quad * 8);
        #pragma unroll
        for (int nt = 0; nt < 4; ++nt) {
            int row = nt * 16 + li;
            int gp  = quad ^ ((row >> 3) & 3);
            bf16x8 bb = *(const bf16x8*)&Xt[p][row][gp * 8];
            acc[0][nt] = __builtin_amdgcn_mfma_f32_16x16x32_bf16(a0, bb, acc[0][nt], 0, 0, 0);
            if (two)
                acc[1][nt] = __builtin_amdgcn_mfma_f32_16x16x32_bf16(a1, bb, acc[1][nt], 0, 0, 0);
        }
        v = vn;
        p ^= 1;
    }

    const float rs = rsqrtf(1.0f + 1e-5f);
    const int nm = two ? 2 : 1;
    for (int mt = 0; mt < nm; ++mt) {
        #pragma unroll
        for (int r = 0; r < 4; ++r) {
            int o = o0 + mt * 64 + wv * 16 + quad * 4 + r;
            float bi = bias ? bias[o] : 0.f;
            float sc = bng ? bng[o] * rs : 1.f;
            float sh = bnb ? bnb[o] : 0.f;
            #pragma unroll
            for (int nt = 0; nt < 4; ++nt) {
                float val = acc[mt][nt][r] + bi;
                val = val * sc + sh;
                if (lrelu) val = (val >= 0.f) ? val : 0.2f * val;
                int s = s0 + nt * 16 + li;
                Y[((size_t)b * O + o) * S_SP + s] = (bf16)val;
            }
        }
    }
}

// ---------------------------------------------------------------------------
// Generic conv1x1 (la_w2, final PAD conv): XCD-chunked 1D grid 8*98*NSEC,
// MT m-tiles per block, same dbuf+prefetch pipeline.
// ---------------------------------------------------------------------------
template<typename TX, typename TY, int CIN, int MT, int NSEC, bool LRELU, bool PAD_OUT>
__global__ __launch_bounds__(256)
void conv1x1_kernel(const TX* __restrict__ X, const float* __restrict__ W,
                    const float* __restrict__ bias, const float* __restrict__ bng,
                    const float* __restrict__ bnb, TY* __restrict__ Y, int O)
{
    __shared__ bf16 Xt[2][64][72];
    const int wg  = blockIdx.x;
    const int xcd = wg & 7;
    const int idx = wg >> 3;
    const int sec = idx % NSEC;
    const int t   = idx / NSEC;
    const int tile = xcd * 98 + t;
    const int s0  = (tile % 49) * 64;
    const int b   = tile / 49;
    const int o0  = sec * (MT * 64);
    const int tid = threadIdx.x;
    const int wv = tid >> 6, lane = tid & 63, li = lane & 15, quad = lane >> 4;

    const TX* Xb = X + (size_t)b * CIN * S_SP;

    f32x4 acc[MT][4];
    #pragma unroll
    for (int mt = 0; mt < MT; ++mt)
        #pragma unroll
        for (int nt = 0; nt < 4; ++nt) acc[mt][nt] = f32x4{0.f, 0.f, 0.f, 0.f};

    const int cl  = tid >> 3;
    const int sj  = (tid & 7) * 8;
    const int g   = cl >> 3;
    const int clo = cl & 7;
    const TX* xp = Xb + (size_t)cl * S_SP + s0 + sj;

    raw8<TX> v = loadraw(xp);
    int p = 0;
    #pragma unroll
    for (int k0 = 0; k0 < CIN; k0 += 32) {
        #pragma unroll
        for (int u = 0; u < 8; ++u) {
            int r  = sj + u;
            int gp = g ^ ((r >> 3) & 3);
            Xt[p][r][gp * 8 + clo] = elem8(v, u);
        }
        raw8<TX> vn = v;
        if (k0 + 32 < CIN) vn = loadraw(xp + (size_t)(k0 + 32) * S_SP);
        __syncthreads();
        bf16x8 a[MT];
        #pragma unroll
        for (int mt = 0; mt < MT; ++mt)
            a[mt] = load8(W + (size_t)(o0 + mt * 64 + wv * 16 + li) * CIN + k0 + quad * 8);
        #pragma unroll
        for (int nt = 0; nt < 4; ++nt) {
            int row = nt * 16 + li;
            int gp  = quad ^ ((row >> 3) & 3);
            bf16x8 bb = *(const bf16x8*)&Xt[p][row][gp * 8];
            #pragma unroll
            for (int mt = 0; mt < MT; ++mt)
                acc[mt][nt] = __builtin_amdgcn_mfma_f32_16x16x32_bf16(a[mt], bb, acc[mt][nt], 0, 0, 0);
        }
        v = vn;
        p ^= 1;
    }

    const float rs = rsqrtf(1.0f + 1e-5f);
    #pragma unroll
    for (int mt = 0; mt < MT; ++mt) {
        #pragma unroll
        for (int r = 0; r < 4; ++r) {
            int o = o0 + mt * 64 + wv * 16 + quad * 4 + r;
            float bi = bias ? bias[o] : 0.f;
            float sc = bng ? bng[o] * rs : 1.f;
            float sh = bnb ? bnb[o] : 0.f;
            #pragma unroll
            for (int nt = 0; nt < 4; ++nt) {
                float val = acc[mt][nt][r] + bi;
                val = val * sc + sh;
                if (LRELU) val = (val >= 0.f) ? val : 0.2f * val;
                int s = s0 + nt * 16 + li;
                if (!PAD_OUT) {
                    Y[((size_t)b * O + o) * S_SP + s] = (TY)val;
                } else {
                    int rr = s / 56, cc = s % 56;
                    Y[(((size_t)b * O + o) * 58 + rr + 1) * 58 + cc + 1] = (TY)val;
                }
            }
        }
    }
}

// ---------------------------------------------------------------------------
// FUSED attention per (b,c): local QK^T->softmax->PV, then global softmax->PV,
// single F write. Vt group-swizzled. grid 4096 x 256.
// ---------------------------------------------------------------------------
__global__ __launch_bounds__(256)
void attn_kernel(const bf16* __restrict__ Q, const bf16* __restrict__ K,
                 const bf16* __restrict__ V, const float* __restrict__ gq,
                 const bf16* __restrict__ GK, const bf16* __restrict__ GV,
                 bf16* __restrict__ F)
{
    __shared__ bf16 Qs[64][72], Ks[64][72], Vt[64][72], Ps[64][72];
    const int bc  = blockIdx.x;
    const int tid = threadIdx.x;
    const int wv = tid >> 6, lane = tid & 63, li = lane & 15, quad = lane >> 4;
    const int m0 = wv * 16;

    #pragma unroll
    for (int i = tid; i < 64 * 36; i += 256) {
        ((uint32_t*)Qs)[i] = 0; ((uint32_t*)Ks)[i] = 0;
        ((uint32_t*)Vt)[i] = 0; ((uint32_t*)Ps)[i] = 0;
    }
    __syncthreads();

    const bf16* Qp = Q + (size_t)bc * S_SP;
    const bf16* Kp = K + (size_t)bc * S_SP;
    const bf16* Vp = V + (size_t)bc * S_SP;
    for (int idx = tid; idx < 392; idx += 256) {   // 56 rows * 7 chunks of 8
        int r = idx / 7, cj = (idx % 7) * 8;
        *(bf16x8*)&Qs[r][cj] = *(const bf16x8*)(Qp + r * 56 + cj);
        *(bf16x8*)&Ks[r][cj] = *(const bf16x8*)(Kp + r * 56 + cj);
        bf16x8 vv = *(const bf16x8*)(Vp + r * 56 + cj);
        int q = r >> 3, rlo = r & 7;               // Vt[w=cj+u][swz(v=r)]
        #pragma unroll
        for (int u = 0; u < 8; ++u) {
            int row = cj + u;
            int gp  = q ^ ((row >> 3) & 3);
            Vt[row][gp * 8 + rlo] = vv[u];
        }
    }

    // ---- phase-2 prefetch: GV chunks (written to LDS after local PV) ----
    const float gs = gq[bc];
    const bf16* GVp = GV + (size_t)bc * S_SP;
    const bf16* GKp = GK + (size_t)bc * S_SP;
    const int ra  = tid / 7,            cja = (tid % 7) * 8;
    const bool hasb = tid < 136;        // idx = tid + 256 < 392
    const int rb  = (tid + 256) / 7,    cjb = ((tid + 256) % 7) * 8;
    bf16x8 gva = *(const bf16x8*)(GVp + ra * 56 + cja);
    bf16x8 gvb = hasb ? *(const bf16x8*)(GVp + rb * 56 + cjb) : bf16x8{};
    __syncthreads();

    // S = Q K^T
    f32x4 sacc[4];
    #pragma unroll
    for (int nt = 0; nt < 4; ++nt) sacc[nt] = f32x4{0.f, 0.f, 0.f, 0.f};
    #pragma unroll
    for (int k0 = 0; k0 < 64; k0 += 32) {
        bf16x8 a = *(const bf16x8*)&Qs[m0 + li][k0 + quad * 8];
        #pragma unroll
        for (int nt = 0; nt < 4; ++nt) {
            bf16x8 bb = *(const bf16x8*)&Ks[nt * 16 + li][k0 + quad * 8];
            sacc[nt] = __builtin_amdgcn_mfma_f32_16x16x32_bf16(a, bb, sacc[nt], 0, 0, 0);
        }
    }

    // local row softmax
    #pragma unroll
    for (int r = 0; r < 4; ++r) {
        float e[4]; float m = -3e38f;
        #pragma unroll
        for (int nt = 0; nt < 4; ++nt) {
            int v = nt * 16 + li;
            float x = (v < 56) ? sacc[nt][r] * SCALE_V : -3e38f;
            e[nt] = x; m = fmaxf(m, x);
        }
        m = fmaxf(m, __shfl_xor(m, 1)); m = fmaxf(m, __shfl_xor(m, 2));
        m = fmaxf(m, __shfl_xor(m, 4)); m = fmaxf(m, __shfl_xor(m, 8));
        float s = 0.f;
        #pragma unroll
        for (int nt = 0; nt < 4; ++nt) {
            float pp = (nt * 16 + li < 56) ? __expf(e[nt] - m) : 0.f;
            e[nt] = pp; s += pp;
        }
        s += __shfl_xor(s, 1); s += __shfl_xor(s, 2);
        s += __shfl_xor(s, 4); s += __shfl_xor(s, 8);
        float inv = 1.f / s;
        int row = m0 + quad * 4 + r;
        #pragma unroll
        for (int nt = 0; nt < 4; ++nt) Ps[row][nt * 16 + li] = (bf16)(e[nt] * inv);
    }

    // ---- phase-2 prefetch: GK values for the global softmax (overlaps PV) ----
    float gkv[4][4];
    #pragma unroll
    for (int r = 0; r < 4; ++r) {
        int row = m0 + quad * 4 + r;
        int hrow = (row < 56) ? row : 0;
        #pragma unroll
        for (int nt = 0; nt < 4; ++nt) {
            int v = nt * 16 + li;
            gkv[r][nt] = (v < 56) ? bf2f(GKp[hrow * 56 + v]) : 0.f;
        }
    }
    __syncthreads();

    // oacc = P V
    f32x4 oacc[4];
    #pragma unroll
    for (int nt = 0; nt < 4; ++nt) oacc[nt] = f32x4{0.f, 0.f, 0.f, 0.f};
    #pragma unroll
    for (int k0 = 0; k0 < 64; k0 += 32) {
        bf16x8 a = *(const bf16x8*)&Ps[m0 + li][k0 + quad * 8];
        int kq = (k0 >> 3) + quad;
        #pragma unroll
        for (int nt = 0; nt < 4; ++nt) {
            int row = nt * 16 + li;
            int gp  = kq ^ ((row >> 3) & 3);
            bf16x8 bb = *(const bf16x8*)&Vt[row][gp * 8];
            oacc[nt] = __builtin_amdgcn_mfma_f32_16x16x32_bf16(a, bb, oacc[nt], 0, 0, 0);
        }
    }

    // ---- phase 2: global attention ----
    __syncthreads();

    {
        int q = ra >> 3, rlo = ra & 7;
        #pragma unroll
        for (int u = 0; u < 8; ++u) {
            int row = cja + u;
            int gp  = q ^ ((row >> 3) & 3);
            Vt[row][gp * 8 + rlo] = gva[u];
        }
        if (hasb) {
            int qb = rb >> 3, rblo = rb & 7;
            #pragma unroll
            for (int u = 0; u < 8; ++u) {
                int row = cjb + u;
                int gp  = qb ^ ((row >> 3) & 3);
                Vt[row][gp * 8 + rblo] = gvb[u];
            }
        }
    }

    #pragma unroll
    for (int r = 0; r < 4; ++r) {
        float e[4]; float m = -3e38f;
        #pragma unroll
        for (int nt = 0; nt < 4; ++nt) {
            int v = nt * 16 + li;
            float x = (v < 56) ? gs * gkv[r][nt] : -3e38f;
            e[nt] = x; m = fmaxf(m, x);
        }
        m = fmaxf(m, __shfl_xor(m, 1)); m = fmaxf(m, __shfl_xor(m, 2));
        m = fmaxf(m, __shfl_xor(m, 4)); m = fmaxf(m, __shfl_xor(m, 8));
        float s = 0.f;
        #pragma unroll
        for (int nt = 0; nt < 4; ++nt) {
            float pp = (nt * 16 + li < 56) ? __expf(e[nt] - m) : 0.f;
            e[nt] = pp; s += pp;
        }
        s += __shfl_xor(s, 1); s += __shfl_xor(s, 2);
        s += __shfl_xor(s, 4); s += __shfl_xor(s, 8);
        float inv = 1.f / s;
        int row = m0 + quad * 4 + r;
        #pragma unroll
        for (int nt = 0; nt < 4; ++nt) Ps[row][nt * 16 + li] = (bf16)(e[nt] * inv);
    }
    __syncthreads();

    // oacc += P_g GV
    #pragma unroll
    for (int k0 = 0; k0 < 64; k0 += 32) {
        bf16x8 a = *(const bf16x8*)&Ps[m0 + li][k0 + quad * 8];
        int kq = (k0 >> 3) + quad;
        #pragma unroll
        for (int nt = 0; nt < 4; ++nt) {
            int row = nt * 16 + li;
            int gp  = kq ^ ((row >> 3) & 3);
            bf16x8 bb = *(const bf16x8*)&Vt[row][gp * 8];
            oacc[nt] = __builtin_amdgcn_mfma_f32_16x16x32_bf16(a, bb, oacc[nt], 0, 0, 0);
        }
    }

    bf16* Fp = F + (size_t)bc * S_SP;
    #pragma unroll
    for (int r = 0; r < 4; ++r) {
        int h = m0 + quad * 4 + r;
        #pragma unroll
        for (int nt = 0; nt < 4; ++nt) {
            int w = nt * 16 + li;
            if (h < 56 && w < 56) Fp[h * 56 + w] = (bf16)oacc[nt][r];
        }
    }
}

// ---------------------------------------------------------------------------
__global__ __launch_bounds__(256)
void spatial_mean_kernel(const float* __restrict__ X, float* __restrict__ out)
{
    int bc = blockIdx.x, tid = threadIdx.x;
    const float* p = X + (size_t)bc * S_SP;
    float s = 0.f;
    for (int i = tid; i < S_SP; i += 256) s += p[i];
    for (int off = 32; off; off >>= 1) s += __shfl_down(s, off, 64);
    __shared__ float ws[4];
    if ((tid & 63) == 0) ws[tid >> 6] = s;
    __syncthreads();
    if (tid == 0) out[bc] = (ws[0] + ws[1] + ws[2] + ws[3]) * (1.0f / S_SP);
}

// Tiny global-branch MLP: grid 16 (per batch), 256 threads.
__global__ __launch_bounds__(256)
void gq_kernel(const float* __restrict__ pmean,
               const float* c11w, const float* c11b,
               const float* gaw1, const float* gab1, const float* gag1, const float* gabe1,
               const float* gaw2, const float* gab2, const float* gag2, const float* gabe2,
               float* __restrict__ gq)
{
    __shared__ float pm[256], p2[256], hh[64];
    int b = blockIdx.x, t = threadIdx.x;
    pm[t] = pmean[b * 256 + t];
    __syncthreads();
    float a = c11b[t];
    for (int c = 0; c < 256; ++c) a += c11w[t * 256 + c] * pm[c];
    p2[t] = a;
    __syncthreads();
    const float rs = rsqrtf(1.0f + 1e-5f);
    if (t < 64) {
        float h = gab1[t];
        for (int c = 0; c < 256; ++c) h += gaw1[t * 256 + c] * p2[c];
        h = h * (gag1[t] * rs) + gabe1[t];
        hh[t] = (h >= 0.f) ? h : 0.2f * h;
    }
    __syncthreads();
    float g = gab2[t];
    for (int i = 0; i < 64; ++i) g += gaw2[t * 64 + i] * hh[i];
    g = g * (gag2[t] * rs) + gabe2[t];
    gq[b * 256 + t] = g * SCALE_V;  // attention SCALE folded in
}

// Border-only fill: 228 border elems per 58x58 image (interior written by conv).
__global__ __launch_bounds__(256)
void fill_border_kernel(float* __restrict__ out, const float* __restrict__ c1b)
{
    int idx = blockIdx.x * 256 + threadIdx.x;
    int e  = idx % 228;
    int bo = idx / 228;
    if (bo >= 16 * 256) return;
    int o = bo & 255;
    int r, c;
    if (e < 58)       { r = 0;  c = e; }
    else if (e < 116) { r = 57; c = e - 58; }
    else { int t = e - 116; r = 1 + (t >> 1); c = (t & 1) * 57; }
    out[(size_t)bo * 3364 + r * 58 + c] = c1b[o];
}

// ---------------------------------------------------------------------------
extern "C" void kernel_launch(void* const* d_in, const int* in_sizes, int n_in,
                              void* d_out, int out_size, void* d_ws, size_t ws_size,
                              hipStream_t stream)
{
    (void)in_sizes; (void)n_in; (void)out_size; (void)ws_size;
    const float* x_s   = (const float*)d_in[0];
    const float* x_fq  = (const float*)d_in[1];
    const float* x_mt  = (const float*)d_in[2];
    const float* la_w1 = (const float*)d_in[3];
    const float* la_b1 = (const float*)d_in[4];
    const float* la_g1 = (const float*)d_in[5];
    const float* la_be1= (const float*)d_in[6];
    const float* la_w2 = (const float*)d_in[7];
    const float* la_b2 = (const float*)d_in[8];
    const float* la_g2 = (const float*)d_in[9];
    const float* la_be2= (const float*)d_in[10];
    const float* lk_w  = (const float*)d_in[11];
    const float* lk_b  = (const float*)d_in[12];
    const float* lv_w  = (const float*)d_in[13];
    const float* ga_w1 = (const float*)d_in[14];
    const float* ga_b1 = (const float*)d_in[15];
    const float* ga_g1 = (const float*)d_in[16];
    const float* ga_be1= (const float*)d_in[17];
    const float* ga_w2 = (const float*)d_in[18];
    const float* ga_b2 = (const float*)d_in[19];
    const float* ga_g2 = (const float*)d_in[20];
    const float* ga_be2= (const float*)d_in[21];
    const float* gk_w  = (const float*)d_in[22];
    const float* gk_b  = (const float*)d_in[23];
    const float* gv_w  = (const float*)d_in[24];
    const float* c11_w = (const float*)d_in[25];
    const float* c11_b = (const float*)d_in[26];
    const float* c1_w  = (const float*)d_in[27];
    const float* c1_b  = (const float*)d_in[28];
    float* out = (float*)d_out;

    char* ws = (char*)d_ws;
    const size_t SZ = (size_t)16 * 256 * S_SP * 2;       // 25,690,112 B (bf16)
    bf16* Q  = (bf16*)(ws);                              // aliased as F below
    bf16* K  = (bf16*)(ws + SZ);
    bf16* V  = (bf16*)(ws + 2 * SZ);
    bf16* GK = (bf16*)(ws + 3 * SZ);
    bf16* GV = (bf16*)(ws + 4 * SZ);
    bf16* Hd = (bf16*)(ws + 5 * SZ);                     // 16*64*3136 bf16
    float* pmean = (float*)(ws + 5 * SZ + (size_t)16 * 64 * S_SP * 2);
    float* gq    = pmean + 16 * 256;
    bf16* F  = Q;  // safe alias: each attn block reads only its own bc slice of Q
                   // (staged before any write) and writes only its own bc slice of F

    dim3 blk(256);
    // output border only (interior fully written by final conv)
    fill_border_kernel<<<dim3(3648), blk, 0, stream>>>(out, c1_b);

    // ---- local branch projections: lk, lv, la_w1 fused over x_s ----
    conv_multi_kernel<5><<<dim3(8 * 98 * 5), blk, 0, stream>>>(
        x_s, lk_w, lk_b, K, lv_w, V,
        la_w1, la_b1, la_g1, la_be1, Hd);
    conv1x1_kernel<bf16, bf16, 64, 2, 2, false, false><<<dim3(8 * 98 * 2), blk, 0, stream>>>(
        Hd, la_w2, la_b2, la_g2, la_be2, Q, 256);

    // ---- global branch projections: gk, gv fused over x_fq ----
    spatial_mean_kernel<<<dim3(4096), blk, 0, stream>>>(x_mt, pmean);
    gq_kernel<<<dim3(16), blk, 0, stream>>>(pmean, c11_w, c11_b,
        ga_w1, ga_b1, ga_g1, ga_be1, ga_w2, ga_b2, ga_g2, ga_be2, gq);
    conv_multi_kernel<4><<<dim3(8 * 98 * 4), blk, 0, stream>>>(
        x_fq, gk_w, gk_b, GK, gv_w, GV,
        nullptr, nullptr, nullptr, nullptr, nullptr);

    // ---- fused local+global attention, writes F once ----
    attn_kernel<<<dim3(4096), blk, 0, stream>>>(Q, K, V, gq, GK, GV, F);

    // ---- output conv (writes interior of padded 58x58) ----
    conv1x1_kernel<bf16, float, 256, 2, 2, false, true><<<dim3(8 * 98 * 2), blk, 0, stream>>>(
        F, c1_w, c1_b, nullptr, nullptr, out, 256);
}

// Round 6
// 442.372 us; speedup vs baseline: 1.3181x; 1.1236x over previous
//
#include <hip/hip_runtime.h>
#include <hip/hip_bf16.h>

typedef __bf16 bf16;
typedef __bf16 bf16x8 __attribute__((ext_vector_type(8)));
typedef float  f32x4  __attribute__((ext_vector_type(4)));

#define S_SP 3136              // 56*56
#define SCALE_V (1.0f/896.0f)  // (56*56*256)^-0.5, exact (896^2 = 802816)

// bf16 weight workspace segment offsets (elements)
#define OFF_LK   0
#define OFF_LV   65536
#define OFF_LA1  131072
#define OFF_GK   147456
#define OFF_GV   212992
#define OFF_LA2  278528
#define OFF_C1   294912
#define WTOT     360448

__device__ __forceinline__ float bf2f(bf16 x) { return (float)x; }

__device__ __forceinline__ bf16x8 load8(const float* p) {
    f32x4 a = *(const f32x4*)p;
    f32x4 b = *(const f32x4*)(p + 4);
    bf16x8 r;
    r[0] = (bf16)a[0]; r[1] = (bf16)a[1]; r[2] = (bf16)a[2]; r[3] = (bf16)a[3];
    r[4] = (bf16)b[0]; r[5] = (bf16)b[1]; r[6] = (bf16)b[2]; r[7] = (bf16)b[3];
    return r;
}
__device__ __forceinline__ bf16x8 load8(const bf16* p) { return *(const bf16x8*)p; }

// ---------------------------------------------------------------------------
// Weight pre-convert f32 -> bf16 (one pass, grid 1408 x 256 exact).
// ---------------------------------------------------------------------------
__global__ __launch_bounds__(256)
void wprep_kernel(const float* __restrict__ lk, const float* __restrict__ lv,
                  const float* __restrict__ la1, const float* __restrict__ gk,
                  const float* __restrict__ gv, const float* __restrict__ la2,
                  const float* __restrict__ c1, bf16* __restrict__ dst)
{
    int i = blockIdx.x * 256 + threadIdx.x;      // 0..360447
    const float* s; int off;
    if      (i < OFF_LV)  { s = lk;  off = i; }
    else if (i < OFF_LA1) { s = lv;  off = i - OFF_LV; }
    else if (i < OFF_GK)  { s = la1; off = i - OFF_LA1; }
    else if (i < OFF_GV)  { s = gk;  off = i - OFF_GK; }
    else if (i < OFF_LA2) { s = gv;  off = i - OFF_GV; }
    else if (i < OFF_C1)  { s = la2; off = i - OFF_LA2; }
    else                  { s = c1;  off = i - OFF_C1; }
    dst[i] = (bf16)s[off];
}

// ---------------------------------------------------------------------------
// Merged 9-section conv1x1 (CIN=256) over x_s (sec 0..4) and x_fq (sec 5..8).
// XCD-chunked 1D grid 8*98*9: xcd=wg&7, idx=wg>>3, sec=idx%9, tile=xcd*98+idx/9
//  -> all 9 sections of a tile on the SAME XCD = shared L2 (R5: FETCH 131->29MB).
// KEY R6 change: the whole X strip (8 slabs) is loaded to REGISTERS UPFRONT
// (32 VGPR as bf16), so the K-loop has NO in-loop X global load -- the
// compiler's vmcnt(0)-before-barrier drain (which exposed ~700cy HBM latency
// per K-step in R4/R5) has nothing left to drain. W is bf16 (wprep) and
// prefetched one step ahead (L2-hot, hidden under ds_write+MFMA).
// ---------------------------------------------------------------------------
__global__ __launch_bounds__(256)
void conv_multi_kernel(const float* __restrict__ xs, const float* __restrict__ xfq,
                       const bf16* __restrict__ Wbf,
                       const float* __restrict__ lk_b,
                       const float* __restrict__ la_b1, const float* __restrict__ la_g1,
                       const float* __restrict__ la_be1,
                       const float* __restrict__ gk_b,
                       bf16* __restrict__ K, bf16* __restrict__ V, bf16* __restrict__ Hd,
                       bf16* __restrict__ GK, bf16* __restrict__ GV)
{
    __shared__ bf16 Xt[2][64][72];
    const int wg  = blockIdx.x;
    const int xcd = wg & 7;
    const int idx = wg >> 3;
    const int sec = idx % 9;
    const int t   = idx / 9;
    const int tile = xcd * 98 + t;          // 0..783
    const int s0  = (tile % 49) * 64;
    const int b   = tile / 49;
    const int tid = threadIdx.x;
    const int wv = tid >> 6, lane = tid & 63, li = lane & 15, quad = lane >> 4;

    // block-uniform section select
    const float* X; const bf16* W;
    const float* bias = nullptr; const float* bng = nullptr; const float* bnb = nullptr;
    bf16* Y; int o0 = 0, O = 256; bool two = true, lrelu = false;
    if (sec < 2)      { X = xs;  W = Wbf + OFF_LK; bias = lk_b; Y = K;  o0 = sec * 128; }
    else if (sec < 4) { X = xs;  W = Wbf + OFF_LV;              Y = V;  o0 = (sec - 2) * 128; }
    else if (sec == 4){ X = xs;  W = Wbf + OFF_LA1; bias = la_b1; bng = la_g1; bnb = la_be1;
                        Y = Hd; O = 64; two = false; lrelu = true; }
    else if (sec < 7) { X = xfq; W = Wbf + OFF_GK; bias = gk_b; Y = GK; o0 = (sec - 5) * 128; }
    else              { X = xfq; W = Wbf + OFF_GV;              Y = GV; o0 = (sec - 7) * 128; }

    const int cl  = tid >> 3;            // 0..31
    const int sj  = (tid & 7) * 8;
    const int g   = cl >> 3;             // column group 0..3
    const int clo = cl & 7;

    // ---- load the whole X strip upfront: 8 slabs x bf16x8 = 32 VGPR ----
    const float* xp = X + (size_t)b * 256 * S_SP + (size_t)cl * S_SP + s0 + sj;
    bf16x8 xr[8];
    #pragma unroll
    for (int i = 0; i < 8; ++i) xr[i] = load8(xp + (size_t)i * 32 * S_SP);

    f32x4 acc[2][4];
    #pragma unroll
    for (int mt = 0; mt < 2; ++mt)
        #pragma unroll
        for (int nt = 0; nt < 4; ++nt) acc[mt][nt] = f32x4{0.f, 0.f, 0.f, 0.f};

    // W fragment pointers (bf16, row stride 256)
    const bf16* wp0 = W + (size_t)(o0 + wv * 16 + li) * 256 + quad * 8;
    const bf16* wp1 = W + (size_t)(o0 + 64 + wv * 16 + li) * 256 + quad * 8;
    bf16x8 a0 = *(const bf16x8*)wp0;
    bf16x8 a1{};
    if (two) a1 = *(const bf16x8*)wp1;

    // stage slab 0
    #pragma unroll
    for (int u = 0; u < 8; ++u) {
        int r = sj + u;
        int gp = g ^ ((r >> 3) & 3);
        Xt[0][r][gp * 8 + clo] = xr[0][u];
    }
    __syncthreads();

    int p = 0;
    #pragma unroll
    for (int k = 0; k < 8; ++k) {
        bf16x8 na0{}, na1{};
        if (k + 1 < 8) {
            na0 = *(const bf16x8*)(wp0 + (k + 1) * 32);
            if (two) na1 = *(const bf16x8*)(wp1 + (k + 1) * 32);
            #pragma unroll
            for (int u = 0; u < 8; ++u) {
                int r = sj + u;
                int gp = g ^ ((r >> 3) & 3);
                Xt[p ^ 1][r][gp * 8 + clo] = xr[k + 1][u];
            }
        }
        #pragma unroll
        for (int nt = 0; nt < 4; ++nt) {
            int row = nt * 16 + li;
            int gp  = quad ^ ((row >> 3) & 3);
            bf16x8 bb = *(const bf16x8*)&Xt[p][row][gp * 8];
            acc[0][nt] = __builtin_amdgcn_mfma_f32_16x16x32_bf16(a0, bb, acc[0][nt], 0, 0, 0);
            if (two)
                acc[1][nt] = __builtin_amdgcn_mfma_f32_16x16x32_bf16(a1, bb, acc[1][nt], 0, 0, 0);
        }
        __syncthreads();
        a0 = na0; a1 = na1; p ^= 1;
    }

    const float rs = rsqrtf(1.0f + 1e-5f);
    const int nm = two ? 2 : 1;
    for (int mt = 0; mt < nm; ++mt) {
        #pragma unroll
        for (int r = 0; r < 4; ++r) {
            int o = o0 + mt * 64 + wv * 16 + quad * 4 + r;
            float bi = bias ? bias[o] : 0.f;
            float sc = bng ? bng[o] * rs : 1.f;
            float sh = bnb ? bnb[o] : 0.f;
            #pragma unroll
            for (int nt = 0; nt < 4; ++nt) {
                float val = acc[mt][nt][r] + bi;
                val = val * sc + sh;
                if (lrelu) val = (val >= 0.f) ? val : 0.2f * val;
                int s = s0 + nt * 16 + li;
                Y[((size_t)b * O + o) * S_SP + s] = (bf16)val;
            }
        }
    }
}

// ---------------------------------------------------------------------------
// Generic conv1x1 (la_w2, final PAD conv), bf16 X input + bf16 W, same
// upfront-X-regs structure. XCD-chunked 1D grid 8*98*NSEC.
// ---------------------------------------------------------------------------
template<typename TY, int CIN, int NSEC, bool LRELU, bool PAD_OUT>
__global__ __launch_bounds__(256)
void conv1x1_kernel(const bf16* __restrict__ X, const bf16* __restrict__ W,
                    const float* __restrict__ bias, const float* __restrict__ bng,
                    const float* __restrict__ bnb, TY* __restrict__ Y, int O)
{
    constexpr int NS = CIN / 32;
    __shared__ bf16 Xt[2][64][72];
    const int wg  = blockIdx.x;
    const int xcd = wg & 7;
    const int idx = wg >> 3;
    const int sec = idx % NSEC;
    const int t   = idx / NSEC;
    const int tile = xcd * 98 + t;
    const int s0  = (tile % 49) * 64;
    const int b   = tile / 49;
    const int o0  = sec * 128;
    const int tid = threadIdx.x;
    const int wv = tid >> 6, lane = tid & 63, li = lane & 15, quad = lane >> 4;

    const int cl  = tid >> 3;
    const int sj  = (tid & 7) * 8;
    const int g   = cl >> 3;
    const int clo = cl & 7;

    const bf16* xp = X + (size_t)b * CIN * S_SP + (size_t)cl * S_SP + s0 + sj;
    bf16x8 xr[NS];
    #pragma unroll
    for (int i = 0; i < NS; ++i) xr[i] = load8(xp + (size_t)i * 32 * S_SP);

    f32x4 acc[2][4];
    #pragma unroll
    for (int mt = 0; mt < 2; ++mt)
        #pragma unroll
        for (int nt = 0; nt < 4; ++nt) acc[mt][nt] = f32x4{0.f, 0.f, 0.f, 0.f};

    const bf16* wp0 = W + (size_t)(o0 + wv * 16 + li) * CIN + quad * 8;
    const bf16* wp1 = W + (size_t)(o0 + 64 + wv * 16 + li) * CIN + quad * 8;
    bf16x8 a0 = *(const bf16x8*)wp0;
    bf16x8 a1 = *(const bf16x8*)wp1;

    #pragma unroll
    for (int u = 0; u < 8; ++u) {
        int r = sj + u;
        int gp = g ^ ((r >> 3) & 3);
        Xt[0][r][gp * 8 + clo] = xr[0][u];
    }
    __syncthreads();

    int p = 0;
    #pragma unroll
    for (int k = 0; k < NS; ++k) {
        bf16x8 na0{}, na1{};
        if (k + 1 < NS) {
            na0 = *(const bf16x8*)(wp0 + (k + 1) * 32);
            na1 = *(const bf16x8*)(wp1 + (k + 1) * 32);
            #pragma unroll
            for (int u = 0; u < 8; ++u) {
                int r = sj + u;
                int gp = g ^ ((r >> 3) & 3);
                Xt[p ^ 1][r][gp * 8 + clo] = xr[k + 1][u];
            }
        }
        #pragma unroll
        for (int nt = 0; nt < 4; ++nt) {
            int row = nt * 16 + li;
            int gp  = quad ^ ((row >> 3) & 3);
            bf16x8 bb = *(const bf16x8*)&Xt[p][row][gp * 8];
            acc[0][nt] = __builtin_amdgcn_mfma_f32_16x16x32_bf16(a0, bb, acc[0][nt], 0, 0, 0);
            acc[1][nt] = __builtin_amdgcn_mfma_f32_16x16x32_bf16(a1, bb, acc[1][nt], 0, 0, 0);
        }
        __syncthreads();
        a0 = na0; a1 = na1; p ^= 1;
    }

    const float rs = rsqrtf(1.0f + 1e-5f);
    #pragma unroll
    for (int mt = 0; mt < 2; ++mt) {
        #pragma unroll
        for (int r = 0; r < 4; ++r) {
            int o = o0 + mt * 64 + wv * 16 + quad * 4 + r;
            float bi = bias ? bias[o] : 0.f;
            float sc = bng ? bng[o] * rs : 1.f;
            float sh = bnb ? bnb[o] : 0.f;
            #pragma unroll
            for (int nt = 0; nt < 4; ++nt) {
                float val = acc[mt][nt][r] + bi;
                val = val * sc + sh;
                if (LRELU) val = (val >= 0.f) ? val : 0.2f * val;
                int s = s0 + nt * 16 + li;
                if (!PAD_OUT) {
                    Y[((size_t)b * O + o) * S_SP + s] = (TY)val;
                } else {
                    int rr = s / 56, cc = s % 56;
                    Y[(((size_t)b * O + o) * 58 + rr + 1) * 58 + cc + 1] = (TY)val;
                }
            }
        }
    }
}

// ---------------------------------------------------------------------------
// FUSED attention per (b,c): local QK^T->softmax->PV, then global softmax->PV,
// single F write. Vt group-swizzled. grid 4096 x 256.
// ---------------------------------------------------------------------------
__global__ __launch_bounds__(256)
void attn_kernel(const bf16* __restrict__ Q, const bf16* __restrict__ K,
                 const bf16* __restrict__ V, const float* __restrict__ gq,
                 const bf16* __restrict__ GK, const bf16* __restrict__ GV,
                 bf16* __restrict__ F)
{
    __shared__ bf16 Qs[64][72], Ks[64][72], Vt[64][72], Ps[64][72];
    const int bc  = blockIdx.x;
    const int tid = threadIdx.x;
    const int wv = tid >> 6, lane = tid & 63, li = lane & 15, quad = lane >> 4;
    const int m0 = wv * 16;

    #pragma unroll
    for (int i = tid; i < 64 * 36; i += 256) {
        ((uint32_t*)Qs)[i] = 0; ((uint32_t*)Ks)[i] = 0;
        ((uint32_t*)Vt)[i] = 0; ((uint32_t*)Ps)[i] = 0;
    }
    __syncthreads();

    const bf16* Qp = Q + (size_t)bc * S_SP;
    const bf16* Kp = K + (size_t)bc * S_SP;
    const bf16* Vp = V + (size_t)bc * S_SP;
    for (int idx = tid; idx < 392; idx += 256) {   // 56 rows * 7 chunks of 8
        int r = idx / 7, cj = (idx % 7) * 8;
        *(bf16x8*)&Qs[r][cj] = *(const bf16x8*)(Qp + r * 56 + cj);
        *(bf16x8*)&Ks[r][cj] = *(const bf16x8*)(Kp + r * 56 + cj);
        bf16x8 vv = *(const bf16x8*)(Vp + r * 56 + cj);
        int q = r >> 3, rlo = r & 7;               // Vt[w=cj+u][swz(v=r)]
        #pragma unroll
        for (int u = 0; u < 8; ++u) {
            int row = cj + u;
            int gp  = q ^ ((row >> 3) & 3);
            Vt[row][gp * 8 + rlo] = vv[u];
        }
    }

    // ---- phase-2 prefetch: GV chunks (written to LDS after local PV) ----
    const float gs = gq[bc];
    const bf16* GVp = GV + (size_t)bc * S_SP;
    const bf16* GKp = GK + (size_t)bc * S_SP;
    const int ra  = tid / 7,            cja = (tid % 7) * 8;
    const bool hasb = tid < 136;        // idx = tid + 256 < 392
    const int rb  = (tid + 256) / 7,    cjb = ((tid + 256) % 7) * 8;
    bf16x8 gva = *(const bf16x8*)(GVp + ra * 56 + cja);
    bf16x8 gvb = hasb ? *(const bf16x8*)(GVp + rb * 56 + cjb) : bf16x8{};
    __syncthreads();

    // S = Q K^T
    f32x4 sacc[4];
    #pragma unroll
    for (int nt = 0; nt < 4; ++nt) sacc[nt] = f32x4{0.f, 0.f, 0.f, 0.f};
    #pragma unroll
    for (int k0 = 0; k0 < 64; k0 += 32) {
        bf16x8 a = *(const bf16x8*)&Qs[m0 + li][k0 + quad * 8];
        #pragma unroll
        for (int nt = 0; nt < 4; ++nt) {
            bf16x8 bb = *(const bf16x8*)&Ks[nt * 16 + li][k0 + quad * 8];
            sacc[nt] = __builtin_amdgcn_mfma_f32_16x16x32_bf16(a, bb, sacc[nt], 0, 0, 0);
        }
    }

    // local row softmax
    #pragma unroll
    for (int r = 0; r < 4; ++r) {
        float e[4]; float m = -3e38f;
        #pragma unroll
        for (int nt = 0; nt < 4; ++nt) {
            int v = nt * 16 + li;
            float x = (v < 56) ? sacc[nt][r] * SCALE_V : -3e38f;
            e[nt] = x; m = fmaxf(m, x);
        }
        m = fmaxf(m, __shfl_xor(m, 1)); m = fmaxf(m, __shfl_xor(m, 2));
        m = fmaxf(m, __shfl_xor(m, 4)); m = fmaxf(m, __shfl_xor(m, 8));
        float s = 0.f;
        #pragma unroll
        for (int nt = 0; nt < 4; ++nt) {
            float pp = (nt * 16 + li < 56) ? __expf(e[nt] - m) : 0.f;
            e[nt] = pp; s += pp;
        }
        s += __shfl_xor(s, 1); s += __shfl_xor(s, 2);
        s += __shfl_xor(s, 4); s += __shfl_xor(s, 8);
        float inv = 1.f / s;
        int row = m0 + quad * 4 + r;
        #pragma unroll
        for (int nt = 0; nt < 4; ++nt) Ps[row][nt * 16 + li] = (bf16)(e[nt] * inv);
    }

    // ---- phase-2 prefetch: GK values for the global softmax (overlaps PV) ----
    float gkv[4][4];
    #pragma unroll
    for (int r = 0; r < 4; ++r) {
        int row = m0 + quad * 4 + r;
        int hrow = (row < 56) ? row : 0;
        #pragma unroll
        for (int nt = 0; nt < 4; ++nt) {
            int v = nt * 16 + li;
            gkv[r][nt] = (v < 56) ? bf2f(GKp[hrow * 56 + v]) : 0.f;
        }
    }
    __syncthreads();

    // oacc = P V
    f32x4 oacc[4];
    #pragma unroll
    for (int nt = 0; nt < 4; ++nt) oacc[nt] = f32x4{0.f, 0.f, 0.f, 0.f};
    #pragma unroll
    for (int k0 = 0; k0 < 64; k0 += 32) {
        bf16x8 a = *(const bf16x8*)&Ps[m0 + li][k0 + quad * 8];
        int kq = (k0 >> 3) + quad;
        #pragma unroll
        for (int nt = 0; nt < 4; ++nt) {
            int row = nt * 16 + li;
            int gp  = kq ^ ((row >> 3) & 3);
            bf16x8 bb = *(const bf16x8*)&Vt[row][gp * 8];
            oacc[nt] = __builtin_amdgcn_mfma_f32_16x16x32_bf16(a, bb, oacc[nt], 0, 0, 0);
        }
    }

    // ---- phase 2: global attention ----
    __syncthreads();

    {
        int q = ra >> 3, rlo = ra & 7;
        #pragma unroll
        for (int u = 0; u < 8; ++u) {
            int row = cja + u;
            int gp  = q ^ ((row >> 3) & 3);
            Vt[row][gp * 8 + rlo] = gva[u];
        }
        if (hasb) {
            int qb = rb >> 3, rblo = rb & 7;
            #pragma unroll
            for (int u = 0; u < 8; ++u) {
                int row = cjb + u;
                int gp  = qb ^ ((row >> 3) & 3);
                Vt[row][gp * 8 + rblo] = gvb[u];
            }
        }
    }

    #pragma unroll
    for (int r = 0; r < 4; ++r) {
        float e[4]; float m = -3e38f;
        #pragma unroll
        for (int nt = 0; nt < 4; ++nt) {
            int v = nt * 16 + li;
            float x = (v < 56) ? gs * gkv[r][nt] : -3e38f;
            e[nt] = x; m = fmaxf(m, x);
        }
        m = fmaxf(m, __shfl_xor(m, 1)); m = fmaxf(m, __shfl_xor(m, 2));
        m = fmaxf(m, __shfl_xor(m, 4)); m = fmaxf(m, __shfl_xor(m, 8));
        float s = 0.f;
        #pragma unroll
        for (int nt = 0; nt < 4; ++nt) {
            float pp = (nt * 16 + li < 56) ? __expf(e[nt] - m) : 0.f;
            e[nt] = pp; s += pp;
        }
        s += __shfl_xor(s, 1); s += __shfl_xor(s, 2);
        s += __shfl_xor(s, 4); s += __shfl_xor(s, 8);
        float inv = 1.f / s;
        int row = m0 + quad * 4 + r;
        #pragma unroll
        for (int nt = 0; nt < 4; ++nt) Ps[row][nt * 16 + li] = (bf16)(e[nt] * inv);
    }
    __syncthreads();

    // oacc += P_g GV
    #pragma unroll
    for (int k0 = 0; k0 < 64; k0 += 32) {
        bf16x8 a = *(const bf16x8*)&Ps[m0 + li][k0 + quad * 8];
        int kq = (k0 >> 3) + quad;
        #pragma unroll
        for (int nt = 0; nt < 4; ++nt) {
            int row = nt * 16 + li;
            int gp  = kq ^ ((row >> 3) & 3);
            bf16x8 bb = *(const bf16x8*)&Vt[row][gp * 8];
            oacc[nt] = __builtin_amdgcn_mfma_f32_16x16x32_bf16(a, bb, oacc[nt], 0, 0, 0);
        }
    }

    bf16* Fp = F + (size_t)bc * S_SP;
    #pragma unroll
    for (int r = 0; r < 4; ++r) {
        int h = m0 + quad * 4 + r;
        #pragma unroll
        for (int nt = 0; nt < 4; ++nt) {
            int w = nt * 16 + li;
            if (h < 56 && w < 56) Fp[h * 56 + w] = (bf16)oacc[nt][r];
        }
    }
}

// ---------------------------------------------------------------------------
__global__ __launch_bounds__(256)
void spatial_mean_kernel(const float* __restrict__ X, float* __restrict__ out)
{
    int bc = blockIdx.x, tid = threadIdx.x;
    const float* p = X + (size_t)bc * S_SP;
    float s = 0.f;
    for (int i = tid; i < S_SP; i += 256) s += p[i];
    for (int off = 32; off; off >>= 1) s += __shfl_down(s, off, 64);
    __shared__ float ws[4];
    if ((tid & 63) == 0) ws[tid >> 6] = s;
    __syncthreads();
    if (tid == 0) out[bc] = (ws[0] + ws[1] + ws[2] + ws[3]) * (1.0f / S_SP);
}

// Tiny global-branch MLP: grid 16 (per batch), 256 threads.
__global__ __launch_bounds__(256)
void gq_kernel(const float* __restrict__ pmean,
               const float* c11w, const float* c11b,
               const float* gaw1, const float* gab1, const float* gag1, const float* gabe1,
               const float* gaw2, const float* gab2, const float* gag2, const float* gabe2,
               float* __restrict__ gq)
{
    __shared__ float pm[256], p2[256], hh[64];
    int b = blockIdx.x, t = threadIdx.x;
    pm[t] = pmean[b * 256 + t];
    __syncthreads();
    float a = c11b[t];
    for (int c = 0; c < 256; ++c) a += c11w[t * 256 + c] * pm[c];
    p2[t] = a;
    __syncthreads();
    const float rs = rsqrtf(1.0f + 1e-5f);
    if (t < 64) {
        float h = gab1[t];
        for (int c = 0; c < 256; ++c) h += gaw1[t * 256 + c] * p2[c];
        h = h * (gag1[t] * rs) + gabe1[t];
        hh[t] = (h >= 0.f) ? h : 0.2f * h;
    }
    __syncthreads();
    float g = gab2[t];
    for (int i = 0; i < 64; ++i) g += gaw2[t * 64 + i] * hh[i];
    g = g * (gag2[t] * rs) + gabe2[t];
    gq[b * 256 + t] = g * SCALE_V;  // attention SCALE folded in
}

// Border-only fill: 228 border elems per 58x58 image (interior written by conv).
__global__ __launch_bounds__(256)
void fill_border_kernel(float* __restrict__ out, const float* __restrict__ c1b)
{
    int idx = blockIdx.x * 256 + threadIdx.x;
    int e  = idx % 228;
    int bo = idx / 228;
    if (bo >= 16 * 256) return;
    int o = bo & 255;
    int r, c;
    if (e < 58)       { r = 0;  c = e; }
    else if (e < 116) { r = 57; c = e - 58; }
    else { int t = e - 116; r = 1 + (t >> 1); c = (t & 1) * 57; }
    out[(size_t)bo * 3364 + r * 58 + c] = c1b[o];
}

// ---------------------------------------------------------------------------
extern "C" void kernel_launch(void* const* d_in, const int* in_sizes, int n_in,
                              void* d_out, int out_size, void* d_ws, size_t ws_size,
                              hipStream_t stream)
{
    (void)in_sizes; (void)n_in; (void)out_size; (void)ws_size;
    const float* x_s   = (const float*)d_in[0];
    const float* x_fq  = (const float*)d_in[1];
    const float* x_mt  = (const float*)d_in[2];
    const float* la_w1 = (const float*)d_in[3];
    const float* la_b1 = (const float*)d_in[4];
    const float* la_g1 = (const float*)d_in[5];
    const float* la_be1= (const float*)d_in[6];
    const float* la_w2 = (const float*)d_in[7];
    const float* la_b2 = (const float*)d_in[8];
    const float* la_g2 = (const float*)d_in[9];
    const float* la_be2= (const float*)d_in[10];
    const float* lk_w  = (const float*)d_in[11];
    const float* lk_b  = (const float*)d_in[12];
    const float* lv_w  = (const float*)d_in[13];
    const float* ga_w1 = (const float*)d_in[14];
    const float* ga_b1 = (const float*)d_in[15];
    const float* ga_g1 = (const float*)d_in[16];
    const float* ga_be1= (const float*)d_in[17];
    const float* ga_w2 = (const float*)d_in[18];
    const float* ga_b2 = (const float*)d_in[19];
    const float* ga_g2 = (const float*)d_in[20];
    const float* ga_be2= (const float*)d_in[21];
    const float* gk_w  = (const float*)d_in[22];
    const float* gk_b  = (const float*)d_in[23];
    const float* gv_w  = (const float*)d_in[24];
    const float* c11_w = (const float*)d_in[25];
    const float* c11_b = (const float*)d_in[26];
    const float* c1_w  = (const float*)d_in[27];
    const float* c1_b  = (const float*)d_in[28];
    float* out = (float*)d_out;

    char* ws = (char*)d_ws;
    const size_t SZ = (size_t)16 * 256 * S_SP * 2;       // 25,690,112 B (bf16)
    bf16* Q  = (bf16*)(ws);                              // aliased as F below
    bf16* K  = (bf16*)(ws + SZ);
    bf16* V  = (bf16*)(ws + 2 * SZ);
    bf16* GK = (bf16*)(ws + 3 * SZ);
    bf16* GV = (bf16*)(ws + 4 * SZ);
    bf16* Hd = (bf16*)(ws + 5 * SZ);                     // 16*64*3136 bf16
    float* pmean = (float*)(ws + 5 * SZ + (size_t)16 * 64 * S_SP * 2);
    float* gq    = pmean + 16 * 256;
    bf16* Wbf   = (bf16*)(gq + 16 * 256);                // 360448 bf16 (16B-aligned)
    bf16* F  = Q;  // safe alias: each attn block reads only its own bc slice of Q
                   // (staged before any write) and writes only its own bc slice of F

    dim3 blk(256);
    // weight pre-convert (f32 -> bf16), 360448 elems exact
    wprep_kernel<<<dim3(1408), blk, 0, stream>>>(
        lk_w, lv_w, la_w1, gk_w, gv_w, la_w2, c1_w, Wbf);

    // output border only (interior fully written by final conv)
    fill_border_kernel<<<dim3(3648), blk, 0, stream>>>(out, c1_b);

    // global-branch scalars
    spatial_mean_kernel<<<dim3(4096), blk, 0, stream>>>(x_mt, pmean);
    gq_kernel<<<dim3(16), blk, 0, stream>>>(pmean, c11_w, c11_b,
        ga_w1, ga_b1, ga_g1, ga_be1, ga_w2, ga_b2, ga_g2, ga_be2, gq);

    // ---- all five CIN=256 projections in ONE launch (9 sections) ----
    conv_multi_kernel<<<dim3(8 * 98 * 9), blk, 0, stream>>>(
        x_s, x_fq, Wbf, lk_b, la_b1, la_g1, la_be1, gk_b,
        K, V, Hd, GK, GV);

    // la_w2: Hd(64) -> Q(256)
    conv1x1_kernel<bf16, 64, 2, false, false><<<dim3(8 * 98 * 2), blk, 0, stream>>>(
        Hd, Wbf + OFF_LA2, la_b2, la_g2, la_be2, Q, 256);

    // ---- fused local+global attention, writes F once ----
    attn_kernel<<<dim3(4096), blk, 0, stream>>>(Q, K, V, gq, GK, GV, F);

    // ---- output conv (writes interior of padded 58x58) ----
    conv1x1_kernel<float, 256, 2, false, true><<<dim3(8 * 98 * 2), blk, 0, stream>>>(
        F, Wbf + OFF_C1, c1_b, nullptr, nullptr, out, 256);
}